// Round 5
// baseline (1097.895 us; speedup 1.0000x reference)
//
#include <hip/hip_runtime.h>
#include <hip/hip_bf16.h>
#include <math.h>

// ---------------- problem constants ----------------
#define B_    512
#define DIM   128
#define A_    3
#define C_    200000
#define K_    50
#define DELTA 1e-3

typedef __attribute__((ext_vector_type(8))) short bf16x8;
typedef __attribute__((ext_vector_type(4))) float f32x4;

// ---------------- Path A constants ----------------
#define NBIN_A 128          // 16 bins/octave over d2 in [16,4096)
#define CAP_A  1024
#define ROWCH  12500        // 16B chunks per row (200000/16)

// gemm3 geometry: 64b x 64n tile, 8 waves, 3 blocks/CU (49KB LDS).
// NSEG=128 keeps the y-stride (gridDim.x) ≡ 0 mod 8 -> all 8 my-siblings
// of a segment land on the SAME XCD -> keys tile L2 reuse.
#define NSEG3  128
#define TPS3   25           // 64-key tiles per segment; 125 segs active
#define NT3    3125         // 200000/64 exact

// Path A ws offsets (bytes)
#define AOFF_H64   0u
#define AOFF_H32   524288u
#define AOFF_HBF   786432u
#define AOFF_Q2    917504u
#define AOFF_V64   1718272u
#define AOFF_BINS  8022016u
#define NEED_A     (8022016ull + 307200000ull)   // ~315.2 MB

// ---------------- Path B (round-1 fallback) constants ----------------
#define NBIN_B 192
#define CAP_B  768
#define BM_B   64
#define BN_B   128
#define TPC_B  16
#define CHUNK_B (TPC_B*BN_B)
#define NCH_B  ((C_ + CHUNK_B - 1)/CHUNK_B)

#define BOFF_H32   0u
#define BOFF_H64   262144u
#define BOFF_Q2    786432u
#define BOFF_K2    788480u
#define BOFF_HIST  3188480u
#define BOFF_TAU   4368128u
#define BOFF_CNT   4374272u
#define BOFF_V64   4380416u
#define BOFF_CAND  4392704u

static __device__ inline unsigned short f2bf(float x) {
    union { float f; unsigned u; } c; c.f = x;
    unsigned r = (c.u + 0x7FFFu + ((c.u >> 16) & 1u)) >> 16;
    return (unsigned short)r;
}
static __device__ inline unsigned pkbf(float a, float b) {
    __hip_bfloat162 t = __float22bfloat162_rn(make_float2(a, b));
    union { __hip_bfloat162 h; unsigned u; } cv; cv.h = t; return cv.u;
}

// ============ MLP encoder (fp64, matches np-f64 ref) ============
__global__ __launch_bounds__(128) void mlp_kernel(
    const float* __restrict__ x,
    const float* __restrict__ W1, const float* __restrict__ b1,
    const float* __restrict__ W2, const float* __restrict__ b2,
    const float* __restrict__ W3, const float* __restrict__ b3,
    const float* __restrict__ W4, const float* __restrict__ b4,
    float* __restrict__ h32, unsigned short* __restrict__ hbf,
    double* __restrict__ h64, float* __restrict__ q2)
{
    int b = blockIdx.x, t = threadIdx.x;
    __shared__ double s0[DIM], s1[DIM];
    double x0 = (double)x[b*2+0], x1 = (double)x[b*2+1];
    double h = x0*(double)W1[t] + x1*(double)W1[DIM+t] + (double)b1[t];
    s0[t] = h > 0.0 ? h : 0.0;
    __syncthreads();
    double acc = (double)b2[t];
    for (int k = 0; k < DIM; k++) acc += s0[k]*(double)W2[k*DIM+t];
    s1[t] = acc > 0.0 ? acc : 0.0;
    __syncthreads();
    acc = (double)b3[t];
    for (int k = 0; k < DIM; k++) acc += s1[k]*(double)W3[k*DIM+t];
    s0[t] = acc > 0.0 ? acc : 0.0;
    __syncthreads();
    acc = (double)b4[t];
    for (int k = 0; k < DIM; k++) acc += s0[k]*(double)W4[k*DIM+t];
    h64[b*DIM+t] = acc;
    float hf = (float)acc;
    h32[b*DIM+t] = hf;
    hbf[b*DIM+t] = f2bf(hf);
    s1[t] = acc*acc;
    __syncthreads();
    for (int s = 64; s > 0; s >>= 1) { if (t < s) s1[t] += s1[t+s]; __syncthreads(); }
    if (t == 0) q2[b] = (float)s1[0];
}

// ---- gemm3 helpers ----
static __device__ inline void load4(float4 lv[4], const float* __restrict__ ka,
                                    int nrow, int hh) {
    const float4* gp = (const float4*)(ka + (size_t)nrow*DIM) + hh*4;
    #pragma unroll
    for (int qq = 0; qq < 4; qq++) lv[qq] = gp[qq];
}
static __device__ inline void conv_store(const float4 lv[4], char* sBn,
                                         float* k2n, int r, int hh) {
    float ss = 0.f;
    int4 pk0, pk1;
    {
        float4 v0 = lv[0], v1 = lv[1];
        ss += v0.x*v0.x + v0.y*v0.y + v0.z*v0.z + v0.w*v0.w
            + v1.x*v1.x + v1.y*v1.y + v1.z*v1.z + v1.w*v1.w;
        pk0.x = (int)pkbf(v0.x, v0.y); pk0.y = (int)pkbf(v0.z, v0.w);
        pk0.z = (int)pkbf(v1.x, v1.y); pk0.w = (int)pkbf(v1.z, v1.w);
    }
    {
        float4 v0 = lv[2], v1 = lv[3];
        ss += v0.x*v0.x + v0.y*v0.y + v0.z*v0.z + v0.w*v0.w
            + v1.x*v1.x + v1.y*v1.y + v1.z*v1.z + v1.w*v1.w;
        pk1.x = (int)pkbf(v0.x, v0.y); pk1.y = (int)pkbf(v0.z, v0.w);
        pk1.z = (int)pkbf(v1.x, v1.y); pk1.w = (int)pkbf(v1.z, v1.w);
    }
    char* base = sBn + r*256;
    *(int4*)(base + (((hh*2    ) ^ (r & 7)) << 4)) = pk0;
    *(int4*)(base + (((hh*2 + 1) ^ (r & 7)) << 4)) = pk1;
    ss += __shfl_xor(ss, 1, 64);
    ss += __shfl_xor(ss, 2, 64);
    ss += __shfl_xor(ss, 4, 64);
    if (hh == 0) k2n[r] = ss;
}

// ============ Path A: bf16 MFMA distance GEMM -> u8 log-bins ============
// v6: 64b x 64n tile, 3 blocks/CU (24 waves/CU, 75% occ cap), reg->LDS dbuf,
// one barrier per tile, and DEFERRED bins stores: tile t's packed u32s are
// kept in regs across the barrier and stored at the top of iteration t+1, so
// the barrier's vmcnt(0) drain never waits on scattered store retirement.
__global__ __launch_bounds__(512, 6) void gemm3_kernel(
    const float* __restrict__ keys, const unsigned short* __restrict__ hbf,
    const float* __restrict__ q2, unsigned char* __restrict__ bins)
{
    const int seg = blockIdx.x, my = blockIdx.y, a = blockIdx.z;
    const int b0 = my*64;
    const int tid = threadIdx.x;
    const int lane = tid & 63, w = tid >> 6;
    const int lm = lane & 15, kh = lane >> 4;
    const int wn = w & 1, wm = w >> 1;   // wn: n-half(32), wm: b-quarter(16)

    const int tbeg = seg*TPS3;
    int tcnt = NT3 - tbeg;
    if (tcnt <= 0) return;               // segs 125..127 idle
    if (tcnt > TPS3) tcnt = TPS3;

    __shared__ __align__(16) short sA[8192];      // h 64x128 bf16, swizzled
    __shared__ __align__(16) short sB[2][8192];   // keys 64x128 bf16, dbuf
    __shared__ float q2s[64];
    __shared__ float k2s[2][64];

    // stage sA once (same XOR swizzle as frag reads)
    {
        #pragma unroll
        for (int u = 0; u < 2; u++) {
            int idx = tid*2 + u;
            int rr = idx >> 4, cc = idx & 15;
            const int4 gv = ((const int4*)hbf)[(size_t)(b0 + rr)*16 + cc];
            *(int4*)((char*)sA + rr*256 + ((cc ^ (rr & 7)) << 4)) = gv;
        }
        if (tid < 64) q2s[tid] = q2[b0 + tid];
    }

    const int r = tid >> 3, hh = tid & 7;   // 64 rows x 8 x 64B
    const float* ka = keys + (size_t)a*C_*DIM;

    float4 lv[4];
    load4(lv, ka, tbeg*64 + r, hh);
    conv_store(lv, (char*)&sB[0][0], k2s[0], r, hh);
    __syncthreads();   // sA + q2s + tile0 staged

    // loop-invariant store offsets (D row = n, D col = b)
    unsigned char* bp_base = bins + ((size_t)(a*B_ + b0))*C_;
    const int bcol = wm*16 + lm;
    const size_t soff0 = (size_t)bcol*C_ + (wn*32 + 0*16 + kh*4);
    const size_t soff1 = (size_t)bcol*C_ + (wn*32 + 1*16 + kh*4);

    unsigned pk_prev0 = 0, pk_prev1 = 0;
    int n0_prev = 0;

    int cur = 0;
    for (int t = 0; t < tcnt; t++) {
        const int n0 = (tbeg + t)*64;
        const bool more = (t + 1 < tcnt);

        // T14 issue-early: next tile's fp32 loads fly under MFMA phase
        if (more) load4(lv, ka, n0 + 64 + r, hh);
        // deferred store of previous tile's bins (retire during this tile)
        if (t > 0) {
            *(unsigned*)(bp_base + n0_prev + soff0) = pk_prev0;
            *(unsigned*)(bp_base + n0_prev + soff1) = pk_prev1;
        }

        f32x4 acc[2];
        acc[0] = (f32x4){0.f, 0.f, 0.f, 0.f};
        acc[1] = (f32x4){0.f, 0.f, 0.f, 0.f};

        const char* sBc = (const char*)&sB[cur][0];
        #pragma unroll
        for (int kst = 0; kst < 4; kst++) {
            bf16x8 af[2], bfv;
            #pragma unroll
            for (int i = 0; i < 2; i++) {     // A = keys (n rows)
                int nr = wn*32 + i*16 + lm;
                af[i] = *(const bf16x8*)(sBc + nr*256 + ((((kst<<2) + kh) ^ (nr & 7)) << 4));
            }
            {                                 // B = h (b cols)
                int br = wm*16 + lm;
                bfv = *(const bf16x8*)((const char*)sA + br*256 + ((((kst<<2) + kh) ^ (br & 7)) << 4));
            }
            #pragma unroll
            for (int i = 0; i < 2; i++)
                acc[i] = __builtin_amdgcn_mfma_f32_16x16x32_bf16(af[i], bfv, acc[i], 0, 0, 0);
        }

        // compute this tile's packed bins (held in regs across the barrier)
        {
            const float q2v = q2s[bcol];
            #pragma unroll
            for (int i = 0; i < 2; i++) {
                int nl = wn*32 + i*16 + kh*4;
                float4 kq = *(const float4*)&k2s[cur][nl];
                unsigned pk = 0;
                #pragma unroll
                for (int rg = 0; rg < 4; rg++) {
                    float kv = (rg == 0) ? kq.x : (rg == 1) ? kq.y : (rg == 2) ? kq.z : kq.w;
                    float d2v = (q2v + kv) - 2.0f*acc[i][rg];
                    float dc = fminf(fmaxf(d2v, 16.0f), 4095.0f);
                    unsigned bin = (__float_as_uint(dc) >> 19) - 2096u;  // [0,127]
                    pk |= bin << (8*rg);
                }
                if (i == 0) pk_prev0 = pk; else pk_prev1 = pk;
            }
            n0_prev = n0;
        }

        // convert prefetched regs -> other buffer (vmcnt wait lands here,
        // after the MFMA phase covered the load latency)
        if (more) conv_store(lv, (char*)&sB[cur ^ 1][0], k2s[cur ^ 1], r, hh);
        __syncthreads();   // ds_writes visible; reads of sB[cur] retired
        cur ^= 1;
    }
    // final tile's store
    *(unsigned*)(bp_base + n0_prev + soff0) = pk_prev0;
    *(unsigned*)(bp_base + n0_prev + soff1) = pk_prev1;
}

// ============ Path A: fused hist + tau + collect + exact top-K ============
// One block per (b,a) row. v6: wave-partitioned 16-replica histogram
// (rep = wave*4 + lane&3) removes cross-wave same-bin atomic collisions.
// Counts/margin/extraction logic identical to the proven kernels.
__global__ __launch_bounds__(256) void finish_kernel(
    const unsigned char* __restrict__ bins, const float* __restrict__ keys,
    const double* __restrict__ h64, const float* __restrict__ mem_values,
    float* __restrict__ out_values, double* __restrict__ val64)
{
    const int q = blockIdx.x;          // a*B_ + b (bins row)
    const int a = q >> 9, b = q & 511;
    const int p = b*A_ + a;            // output index
    const int tid = threadIdx.x;

    __shared__ unsigned hist_s[NBIN_A*16];
    __shared__ unsigned hc[NBIN_A];
    __shared__ double hd[DIM];
    __shared__ int    cidx[CAP_A];
    __shared__ double d2s[CAP_A];
    __shared__ float  vs[CAP_A];
    __shared__ double redv[4];
    __shared__ int    redi4[4];
    __shared__ double acc_w, acc_wv;
    __shared__ unsigned cnt_s;
    __shared__ int thr_s;

    for (int i = tid; i < NBIN_A*16; i += 256) hist_s[i] = 0;
    for (int i = tid; i < DIM; i += 256) hd[i] = h64[(size_t)b*DIM + i];
    if (tid == 0) { cnt_s = 0; acc_w = 0.0; acc_wv = 0.0; }
    __syncthreads();

    const uint4* row = (const uint4*)(bins + (size_t)q*C_);
    const int rep = ((tid >> 6) << 2) | (tid & 3);   // wave*4 + lane&3
    // scan 1: histogram
    for (int ch = tid; ch < ROWCH; ch += 256) {
        uint4 v = row[ch];
        unsigned d[4] = {v.x, v.y, v.z, v.w};
        #pragma unroll
        for (int e = 0; e < 4; e++) {
            unsigned x = d[e];
            atomicAdd(&hist_s[((x      ) & 127u)*16 + rep], 1u);
            atomicAdd(&hist_s[((x >>  8) & 127u)*16 + rep], 1u);
            atomicAdd(&hist_s[((x >> 16) & 127u)*16 + rep], 1u);
            atomicAdd(&hist_s[((x >> 24) & 127u)*16 + rep], 1u);
        }
    }
    __syncthreads();
    if (tid < NBIN_A) {
        unsigned s = 0;
        #pragma unroll
        for (int r2 = 0; r2 < 16; r2++) s += hist_s[tid*16 + r2];
        hc[tid] = s;
    }
    __syncthreads();
    if (tid == 0) {
        unsigned cum = 0; int jsel = NBIN_A-1;
        for (int j = 0; j < NBIN_A; j++) { cum += hc[j]; if (cum >= K_) { jsel = j; break; } }
        unsigned c1 = cum + (jsel+1 < NBIN_A ? hc[jsel+1] : 0u);
        unsigned c2 = c1  + (jsel+2 < NBIN_A ? hc[jsel+2] : 0u);
        int jt = (c2 <= 768u) ? jsel+2 : jsel+1;   // capture margin
        if (jt > NBIN_A-1) jt = NBIN_A-1;
        thr_s = jt + 1;
    }
    __syncthreads();
    const unsigned thr  = (unsigned)thr_s;         // select bytes < thr
    const unsigned addv = (128u - thr) * 0x01010101u;
    // scan 2: collect candidates
    for (int ch = tid; ch < ROWCH; ch += 256) {
        uint4 v = row[ch];
        unsigned d[4] = {v.x, v.y, v.z, v.w};
        #pragma unroll
        for (int e = 0; e < 4; e++) {
            unsigned m = (d[e] + addv) & 0x80808080u;
            if (m != 0x80808080u) {
                #pragma unroll
                for (int by = 0; by < 4; by++) {
                    if (!((m >> (8*by + 7)) & 1u)) {
                        unsigned pos = atomicAdd(&cnt_s, 1u);
                        if (pos < CAP_A) cidx[pos] = ch*16 + e*4 + by;
                    }
                }
            }
        }
    }
    __syncthreads();
    int n = (int)cnt_s; if (n > CAP_A) n = CAP_A;

    // exact fp64 distances
    for (int i = tid; i < n; i += 256) {
        int c = cidx[i];
        const float4* kr = (const float4*)(keys + ((size_t)a*C_ + c)*DIM);
        double s0 = 0.0, s1 = 0.0;
        #pragma unroll 4
        for (int kq = 0; kq < 32; kq++) {
            float4 kv = kr[kq];
            double d0 = hd[4*kq+0] - (double)kv.x;
            double d1 = hd[4*kq+1] - (double)kv.y;
            double d2 = hd[4*kq+2] - (double)kv.z;
            double d3 = hd[4*kq+3] - (double)kv.w;
            s0 += d0*d0 + d1*d1; s1 += d2*d2 + d3*d3;
        }
        d2s[i] = s0 + s1;
        vs[i]  = mem_values[(size_t)a*C_ + c];
    }
    __syncthreads();

    // serial top-K extraction (shuffle butterfly, 2 barriers/iter)
    int kk = n < K_ ? n : K_;
    for (int t = 0; t < kk; t++) {
        double best = 1e300; int bi = -1;
        for (int i = tid; i < n; i += 256)
            if (d2s[i] < best) { best = d2s[i]; bi = i; }
        #pragma unroll
        for (int off = 32; off > 0; off >>= 1) {
            double ov = __shfl_xor(best, off, 64);
            int    oi = __shfl_xor(bi,   off, 64);
            if (ov < best) { best = ov; bi = oi; }
        }
        int wv = tid >> 6;
        if ((tid & 63) == 0) { redv[wv] = best; redi4[wv] = bi; }
        __syncthreads();
        if (tid == 0) {
            double bv = redv[0]; int wi = redi4[0];
            if (redv[1] < bv) { bv = redv[1]; wi = redi4[1]; }
            if (redv[2] < bv) { bv = redv[2]; wi = redi4[2]; }
            if (redv[3] < bv) { bv = redv[3]; wi = redi4[3]; }
            double d = d2s[wi]; if (d < 0.0) d = 0.0;
            double wgt = 1.0 / (d + DELTA);
            acc_w += wgt; acc_wv += wgt * (double)vs[wi];
            d2s[wi] = 2e300;
        }
        __syncthreads();
    }
    if (tid == 0) {
        double v = acc_wv / acc_w;
        out_values[p] = (float)v;
        val64[p] = v;
    }
}

// ============ Path B (round-1 fallback) kernels ============
__global__ __launch_bounds__(256) void k2_kernel(const float* __restrict__ keys,
                                                 float* __restrict__ k2)
{
    int r = blockIdx.x*4 + (threadIdx.x >> 6);
    int lane = threadIdx.x & 63;
    float2 v = ((const float2*)keys)[(size_t)r*64 + lane];
    float s = v.x*v.x + v.y*v.y;
    #pragma unroll
    for (int off = 32; off > 0; off >>= 1) s += __shfl_down(s, off, 64);
    if (lane == 0) k2[r] = s;
}

template<int MODE>
__global__ __launch_bounds__(256) void pass_kernel(
    const float* __restrict__ keys, const float* __restrict__ h32,
    const float* __restrict__ q2,   const float* __restrict__ k2,
    unsigned* __restrict__ hist,    const float* __restrict__ tau,
    unsigned* __restrict__ cnt,     int* __restrict__ cand)
{
    const int bt = blockIdx.x;
    const int ch = blockIdx.y;
    const int a  = blockIdx.z;
    const int b0 = bt*BM_B;
    const int tid = threadIdx.x;
    const int tx = tid & 31, ty = tid >> 5;

    __shared__ float4 hs4[BM_B*33];
    __shared__ float4 ks4[BN_B*33];
    __shared__ float  q2s[BM_B];
    __shared__ float  taus[BM_B];
    __shared__ unsigned hist_s[MODE == 0 ? BM_B*NBIN_B : 1];

    #pragma unroll
    for (int q = 0; q < BM_B*32/256; q++) {
        int flat = q*256 + tid; int row = flat >> 5, kq = flat & 31;
        hs4[row*33 + kq] = ((const float4*)h32)[(size_t)(b0+row)*32 + kq];
    }
    if (tid < BM_B) {
        q2s[tid] = q2[b0+tid];
        if (MODE == 1) taus[tid] = tau[(b0+tid)*A_ + a];
    }
    if (MODE == 0) for (int i = tid; i < BM_B*NBIN_B; i += 256) hist_s[i] = 0;
    const float* __restrict__ k2g = k2 + (size_t)a*C_;

    for (int t = 0; t < TPC_B; t++) {
        int n0 = ch*CHUNK_B + t*BN_B;
        if (n0 >= C_) break;
        __syncthreads();
        #pragma unroll
        for (int q = 0; q < 16; q++) {
            int flat = q*256 + tid; int row = flat >> 5, kq = flat & 31;
            int nr = n0 + row; if (nr >= C_) nr = C_-1;
            ks4[row*33 + kq] = ((const float4*)keys)[((size_t)a*C_ + nr)*32 + kq];
        }
        __syncthreads();

        float acc[8][4];
        #pragma unroll
        for (int i = 0; i < 8; i++)
            #pragma unroll
            for (int j = 0; j < 4; j++) acc[i][j] = 0.0f;

        for (int kq = 0; kq < 32; kq++) {
            float4 hv[8], kv[4];
            #pragma unroll
            for (int i = 0; i < 8; i++) hv[i] = hs4[(ty*8+i)*33 + kq];
            #pragma unroll
            for (int j = 0; j < 4; j++) kv[j] = ks4[(j*32+tx)*33 + kq];
            #pragma unroll
            for (int i = 0; i < 8; i++)
                #pragma unroll
                for (int j = 0; j < 4; j++)
                    acc[i][j] += hv[i].x*kv[j].x + hv[i].y*kv[j].y
                               + hv[i].z*kv[j].z + hv[i].w*kv[j].w;
        }

        #pragma unroll
        for (int i = 0; i < 8; i++) {
            int bl = ty*8 + i;
            float q2b = q2s[bl];
            #pragma unroll
            for (int j = 0; j < 4; j++) {
                int n = n0 + j*32 + tx;
                if (n < C_) {
                    float d2f = fmaxf(q2b + k2g[n] - 2.0f*acc[i][j], 0.0f);
                    if (MODE == 0) {
                        int bin = (int)(__float_as_uint(d2f + 1.0f) >> 19) - 2032;
                        bin = bin < 0 ? 0 : (bin > NBIN_B-1 ? NBIN_B-1 : bin);
                        atomicAdd(&hist_s[bl*NBIN_B + bin], 1u);
                    } else {
                        if (d2f < taus[bl]) {
                            int p = (b0+bl)*A_ + a;
                            unsigned pos = atomicAdd(&cnt[p], 1u);
                            if (pos < CAP_B) cand[(size_t)p*CAP_B + pos] = n;
                        }
                    }
                }
            }
        }
    }
    if (MODE == 0) {
        __syncthreads();
        for (int i = tid; i < BM_B*NBIN_B; i += 256) {
            unsigned v = hist_s[i];
            if (v) {
                int bl = i / NBIN_B, bin = i % NBIN_B;
                atomicAdd(&hist[(size_t)((b0+bl)*A_ + a)*NBIN_B + bin], v);
            }
        }
    }
}

__global__ __launch_bounds__(256) void tauB_kernel(const unsigned* __restrict__ hist,
                                                   float* __restrict__ tau)
{
    int p = blockIdx.x*256 + threadIdx.x;
    if (p >= B_*A_) return;
    const unsigned* hp = hist + (size_t)p*NBIN_B;
    unsigned cum = 0; int jsel = NBIN_B-1;
    for (int j = 0; j < NBIN_B; j++) { cum += hp[j]; if (cum >= K_) { jsel = j; break; } }
    tau[p] = __uint_as_float((unsigned)(2034 + jsel) << 19) - 1.0f;
}

// ============ Path B: exact fp64 top-K + NEC weighted value ============
__global__ __launch_bounds__(256) void select_kernel(
    const float* __restrict__ keys, const double* __restrict__ h64,
    const float* __restrict__ mem_values,
    const unsigned* __restrict__ cnt, const int* __restrict__ cand,
    float* __restrict__ out_values, double* __restrict__ val64, int cap)
{
    int p = blockIdx.x; int b = p / A_, a = p % A_;
    int tid = threadIdx.x;
    __shared__ double hd[DIM];
    __shared__ double d2s[CAP_A];
    __shared__ float  vs[CAP_A];
    __shared__ double redv[4];
    __shared__ int    redi4[4];
    __shared__ double acc_w, acc_wv;

    for (int i = tid; i < DIM; i += 256) hd[i] = h64[(size_t)b*DIM + i];
    if (tid == 0) { acc_w = 0.0; acc_wv = 0.0; }
    __syncthreads();

    int n = (int)cnt[p]; if (n > cap) n = cap;
    for (int i = tid; i < n; i += 256) {
        int c = cand[(size_t)p*cap + i];
        const float4* kr = (const float4*)(keys + ((size_t)a*C_ + c)*DIM);
        double s0 = 0.0, s1 = 0.0;
        #pragma unroll 4
        for (int kq = 0; kq < 32; kq++) {
            float4 kv = kr[kq];
            double d0 = hd[4*kq+0] - (double)kv.x;
            double d1 = hd[4*kq+1] - (double)kv.y;
            double d2 = hd[4*kq+2] - (double)kv.z;
            double d3 = hd[4*kq+3] - (double)kv.w;
            s0 += d0*d0 + d1*d1; s1 += d2*d2 + d3*d3;
        }
        d2s[i] = s0 + s1;
        vs[i]  = mem_values[(size_t)a*C_ + c];
    }
    __syncthreads();

    int kk = n < K_ ? n : K_;
    for (int t = 0; t < kk; t++) {
        double best = 1e300; int bi = -1;
        for (int i = tid; i < n; i += 256)
            if (d2s[i] < best) { best = d2s[i]; bi = i; }
        #pragma unroll
        for (int off = 32; off > 0; off >>= 1) {
            double ov = __shfl_xor(best, off, 64);
            int    oi = __shfl_xor(bi,   off, 64);
            if (ov < best) { best = ov; bi = oi; }
        }
        int wv = tid >> 6;
        if ((tid & 63) == 0) { redv[wv] = best; redi4[wv] = bi; }
        __syncthreads();
        if (tid == 0) {
            double bv = redv[0]; int wi = redi4[0];
            if (redv[1] < bv) { bv = redv[1]; wi = redi4[1]; }
            if (redv[2] < bv) { bv = redv[2]; wi = redi4[2]; }
            if (redv[3] < bv) { bv = redv[3]; wi = redi4[3]; }
            double d = d2s[wi]; if (d < 0.0) d = 0.0;
            double wgt = 1.0 / (d + DELTA);
            acc_w += wgt; acc_wv += wgt * (double)vs[wi];
            d2s[wi] = 2e300;
        }
        __syncthreads();
    }
    if (tid == 0) {
        double v = acc_wv / acc_w;
        out_values[p] = (float)v;
        val64[p] = v;
    }
}

__global__ void argmax_kernel(const double* __restrict__ val64, float* __restrict__ out)
{
    int b = blockIdx.x*blockDim.x + threadIdx.x;
    if (b >= B_) return;
    double v0 = val64[b*A_+0], v1 = val64[b*A_+1], v2 = val64[b*A_+2];
    int bi = 0; double bv = v0;
    if (v1 > bv) { bv = v1; bi = 1; }
    if (v2 > bv) { bv = v2; bi = 2; }
    out[B_*A_ + b] = (float)bi;
}

// ============ host ============
extern "C" void kernel_launch(void* const* d_in, const int* in_sizes, int n_in,
                              void* d_out, int out_size, void* d_ws, size_t ws_size,
                              hipStream_t stream)
{
    const float* x    = (const float*)d_in[0];
    const float* W1   = (const float*)d_in[1];
    const float* b1   = (const float*)d_in[2];
    const float* W2   = (const float*)d_in[3];
    const float* b2   = (const float*)d_in[4];
    const float* W3   = (const float*)d_in[5];
    const float* b3   = (const float*)d_in[6];
    const float* W4   = (const float*)d_in[7];
    const float* b4   = (const float*)d_in[8];
    const float* keys = (const float*)d_in[9];
    const float* memv = (const float*)d_in[10];

    char* ws = (char*)d_ws;

    if (ws_size >= NEED_A) {
        // -------- Path A: MFMA gemm -> bins -> fused finish --------
        double*         h64  = (double*)        (ws + AOFF_H64);
        float*          h32  = (float*)         (ws + AOFF_H32);
        unsigned short* hbf  = (unsigned short*)(ws + AOFF_HBF);
        float*          q2   = (float*)         (ws + AOFF_Q2);
        double*         v64  = (double*)        (ws + AOFF_V64);
        unsigned char*  bins = (unsigned char*) (ws + AOFF_BINS);

        mlp_kernel<<<B_, 128, 0, stream>>>(x, W1, b1, W2, b2, W3, b3, W4, b4, h32, hbf, h64, q2);
        gemm3_kernel<<<dim3(NSEG3, 8, A_), 512, 0, stream>>>(keys, hbf, q2, bins);
        finish_kernel<<<B_*A_, 256, 0, stream>>>(bins, keys, h64, memv, (float*)d_out, v64);
        argmax_kernel<<<2, 256, 0, stream>>>(v64, (float*)d_out);
    } else {
        // -------- Path B: round-1 proven fp32 two-pass --------
        float*          h32  = (float*)         (ws + BOFF_H32);
        double*         h64  = (double*)        (ws + BOFF_H64);
        float*          q2   = (float*)         (ws + BOFF_Q2);
        float*          k2   = (float*)         (ws + BOFF_K2);
        unsigned*       hist = (unsigned*)      (ws + BOFF_HIST);
        float*          tau  = (float*)         (ws + BOFF_TAU);
        unsigned*       cnt  = (unsigned*)      (ws + BOFF_CNT);
        double*         v64  = (double*)        (ws + BOFF_V64);
        int*            cand = (int*)           (ws + BOFF_CAND);
        unsigned short* hbf  = (unsigned short*)(ws + BOFF_CAND); // scratch

        hipMemsetAsync(ws + BOFF_HIST, 0, (BOFF_CNT + B_*A_*4) - BOFF_HIST, stream);

        mlp_kernel<<<B_, 128, 0, stream>>>(x, W1, b1, W2, b2, W3, b3, W4, b4, h32, hbf, h64, q2);
        k2_kernel<<<(A_*C_)/4, 256, 0, stream>>>(keys, k2);
        pass_kernel<0><<<dim3(B_/BM_B, NCH_B, A_), 256, 0, stream>>>(keys, h32, q2, k2, hist, nullptr, nullptr, nullptr);
        tauB_kernel<<<(B_*A_ + 255)/256, 256, 0, stream>>>(hist, tau);
        pass_kernel<1><<<dim3(B_/BM_B, NCH_B, A_), 256, 0, stream>>>(keys, h32, q2, k2, nullptr, tau, cnt, cand);
        select_kernel<<<B_*A_, 256, 0, stream>>>(keys, h64, memv, cnt, cand, (float*)d_out, v64, CAP_B);
        argmax_kernel<<<2, 256, 0, stream>>>(v64, (float*)d_out);
    }
}

// Round 6
// 1084.506 us; speedup vs baseline: 1.0123x; 1.0123x over previous
//
#include <hip/hip_runtime.h>
#include <hip/hip_bf16.h>
#include <math.h>

// ---------------- problem constants ----------------
#define B_    512
#define DIM   128
#define A_    3
#define C_    200000
#define K_    50
#define DELTA 1e-3

typedef __attribute__((ext_vector_type(8))) short bf16x8;
typedef __attribute__((ext_vector_type(4))) float f32x4;

// ---------------- Path A constants ----------------
#define NBIN_A 128          // 16 bins/octave over d2 in [16,4096)
#define CAP_A  1024
#define ROWCH  12500        // 16B chunks per row (200000/16)

// gemm3 geometry: 64b x 64n tile, 8 waves, 3 blocks/CU (49KB LDS).
// v7: grid = (32,8,3) = 768 blocks = exactly one co-residency wave
// (3/CU x 256 CU). All 8 my-siblings of a segment are CO-RESIDENT and in
// lockstep -> keys tile fetched once. (v6's span 128*8=1024 > 768 window
// put trailing siblings in the next wave -> 2.6x FETCH.) y-stride 32 ≡ 0
// mod 8 keeps siblings on the same XCD.
#define NSEG3  32
#define TPS3   98           // 64-key tiles per segment (32*98=3136 >= 3125)
#define NT3    3125         // 200000/64 exact

// Path A ws offsets (bytes)
#define AOFF_H64   0u
#define AOFF_H32   524288u
#define AOFF_HBF   786432u
#define AOFF_Q2    917504u
#define AOFF_V64   1718272u
#define AOFF_BINS  8022016u
#define NEED_A     (8022016ull + 307200000ull)   // ~315.2 MB

// ---------------- Path B (round-1 fallback) constants ----------------
#define NBIN_B 192
#define CAP_B  768
#define BM_B   64
#define BN_B   128
#define TPC_B  16
#define CHUNK_B (TPC_B*BN_B)
#define NCH_B  ((C_ + CHUNK_B - 1)/CHUNK_B)

#define BOFF_H32   0u
#define BOFF_H64   262144u
#define BOFF_Q2    786432u
#define BOFF_K2    788480u
#define BOFF_HIST  3188480u
#define BOFF_TAU   4368128u
#define BOFF_CNT   4374272u
#define BOFF_V64   4380416u
#define BOFF_CAND  4392704u

static __device__ inline unsigned short f2bf(float x) {
    union { float f; unsigned u; } c; c.f = x;
    unsigned r = (c.u + 0x7FFFu + ((c.u >> 16) & 1u)) >> 16;
    return (unsigned short)r;
}
static __device__ inline unsigned pkbf(float a, float b) {
    __hip_bfloat162 t = __float22bfloat162_rn(make_float2(a, b));
    union { __hip_bfloat162 h; unsigned u; } cv; cv.h = t; return cv.u;
}

// ============ MLP encoder (fp64, matches np-f64 ref) ============
__global__ __launch_bounds__(128) void mlp_kernel(
    const float* __restrict__ x,
    const float* __restrict__ W1, const float* __restrict__ b1,
    const float* __restrict__ W2, const float* __restrict__ b2,
    const float* __restrict__ W3, const float* __restrict__ b3,
    const float* __restrict__ W4, const float* __restrict__ b4,
    float* __restrict__ h32, unsigned short* __restrict__ hbf,
    double* __restrict__ h64, float* __restrict__ q2)
{
    int b = blockIdx.x, t = threadIdx.x;
    __shared__ double s0[DIM], s1[DIM];
    double x0 = (double)x[b*2+0], x1 = (double)x[b*2+1];
    double h = x0*(double)W1[t] + x1*(double)W1[DIM+t] + (double)b1[t];
    s0[t] = h > 0.0 ? h : 0.0;
    __syncthreads();
    double acc = (double)b2[t];
    for (int k = 0; k < DIM; k++) acc += s0[k]*(double)W2[k*DIM+t];
    s1[t] = acc > 0.0 ? acc : 0.0;
    __syncthreads();
    acc = (double)b3[t];
    for (int k = 0; k < DIM; k++) acc += s1[k]*(double)W3[k*DIM+t];
    s0[t] = acc > 0.0 ? acc : 0.0;
    __syncthreads();
    acc = (double)b4[t];
    for (int k = 0; k < DIM; k++) acc += s0[k]*(double)W4[k*DIM+t];
    h64[b*DIM+t] = acc;
    float hf = (float)acc;
    h32[b*DIM+t] = hf;
    hbf[b*DIM+t] = f2bf(hf);
    s1[t] = acc*acc;
    __syncthreads();
    for (int s = 64; s > 0; s >>= 1) { if (t < s) s1[t] += s1[t+s]; __syncthreads(); }
    if (t == 0) q2[b] = (float)s1[0];
}

// ---- gemm3 helpers ----
static __device__ inline void load4(float4 lv[4], const float* __restrict__ ka,
                                    int nrow, int hh) {
    const float4* gp = (const float4*)(ka + (size_t)nrow*DIM) + hh*4;
    #pragma unroll
    for (int qq = 0; qq < 4; qq++) lv[qq] = gp[qq];
}
static __device__ inline void conv_store(const float4 lv[4], char* sBn,
                                         float* k2n, int r, int hh) {
    float ss = 0.f;
    int4 pk0, pk1;
    {
        float4 v0 = lv[0], v1 = lv[1];
        ss += v0.x*v0.x + v0.y*v0.y + v0.z*v0.z + v0.w*v0.w
            + v1.x*v1.x + v1.y*v1.y + v1.z*v1.z + v1.w*v1.w;
        pk0.x = (int)pkbf(v0.x, v0.y); pk0.y = (int)pkbf(v0.z, v0.w);
        pk0.z = (int)pkbf(v1.x, v1.y); pk0.w = (int)pkbf(v1.z, v1.w);
    }
    {
        float4 v0 = lv[2], v1 = lv[3];
        ss += v0.x*v0.x + v0.y*v0.y + v0.z*v0.z + v0.w*v0.w
            + v1.x*v1.x + v1.y*v1.y + v1.z*v1.z + v1.w*v1.w;
        pk1.x = (int)pkbf(v0.x, v0.y); pk1.y = (int)pkbf(v0.z, v0.w);
        pk1.z = (int)pkbf(v1.x, v1.y); pk1.w = (int)pkbf(v1.z, v1.w);
    }
    char* base = sBn + r*256;
    *(int4*)(base + (((hh*2    ) ^ (r & 7)) << 4)) = pk0;
    *(int4*)(base + (((hh*2 + 1) ^ (r & 7)) << 4)) = pk1;
    ss += __shfl_xor(ss, 1, 64);
    ss += __shfl_xor(ss, 2, 64);
    ss += __shfl_xor(ss, 4, 64);
    if (hh == 0) k2n[r] = ss;
}

// ============ Path A: bf16 MFMA distance GEMM -> u8 log-bins ============
// 64b x 64n tile, 3 blocks/CU, reg->LDS dbuf, one barrier per tile, deferred
// bins stores (tile t's packed u32s stored at top of t+1 so the barrier's
// vmcnt(0) drain never waits on scattered store retirement).
__global__ __launch_bounds__(512, 6) void gemm3_kernel(
    const float* __restrict__ keys, const unsigned short* __restrict__ hbf,
    const float* __restrict__ q2, unsigned char* __restrict__ bins)
{
    const int seg = blockIdx.x, my = blockIdx.y, a = blockIdx.z;
    const int b0 = my*64;
    const int tid = threadIdx.x;
    const int lane = tid & 63, w = tid >> 6;
    const int lm = lane & 15, kh = lane >> 4;
    const int wn = w & 1, wm = w >> 1;   // wn: n-half(32), wm: b-quarter(16)

    const int tbeg = seg*TPS3;
    int tcnt = NT3 - tbeg;
    if (tcnt <= 0) return;
    if (tcnt > TPS3) tcnt = TPS3;

    __shared__ __align__(16) short sA[8192];      // h 64x128 bf16, swizzled
    __shared__ __align__(16) short sB[2][8192];   // keys 64x128 bf16, dbuf
    __shared__ float q2s[64];
    __shared__ float k2s[2][64];

    // stage sA once (same XOR swizzle as frag reads)
    {
        #pragma unroll
        for (int u = 0; u < 2; u++) {
            int idx = tid*2 + u;
            int rr = idx >> 4, cc = idx & 15;
            const int4 gv = ((const int4*)hbf)[(size_t)(b0 + rr)*16 + cc];
            *(int4*)((char*)sA + rr*256 + ((cc ^ (rr & 7)) << 4)) = gv;
        }
        if (tid < 64) q2s[tid] = q2[b0 + tid];
    }

    const int r = tid >> 3, hh = tid & 7;   // 64 rows x 8 x 64B
    const float* ka = keys + (size_t)a*C_*DIM;

    float4 lv[4];
    load4(lv, ka, tbeg*64 + r, hh);
    conv_store(lv, (char*)&sB[0][0], k2s[0], r, hh);
    __syncthreads();   // sA + q2s + tile0 staged

    // loop-invariant store offsets (D row = n, D col = b)
    unsigned char* bp_base = bins + ((size_t)(a*B_ + b0))*C_;
    const int bcol = wm*16 + lm;
    const size_t soff0 = (size_t)bcol*C_ + (wn*32 + 0*16 + kh*4);
    const size_t soff1 = (size_t)bcol*C_ + (wn*32 + 1*16 + kh*4);

    unsigned pk_prev0 = 0, pk_prev1 = 0;
    int n0_prev = 0;

    int cur = 0;
    for (int t = 0; t < tcnt; t++) {
        const int n0 = (tbeg + t)*64;
        const bool more = (t + 1 < tcnt);

        // T14 issue-early: next tile's fp32 loads fly under MFMA phase
        if (more) load4(lv, ka, n0 + 64 + r, hh);
        // deferred store of previous tile's bins (retire during this tile)
        if (t > 0) {
            *(unsigned*)(bp_base + n0_prev + soff0) = pk_prev0;
            *(unsigned*)(bp_base + n0_prev + soff1) = pk_prev1;
        }

        f32x4 acc[2];
        acc[0] = (f32x4){0.f, 0.f, 0.f, 0.f};
        acc[1] = (f32x4){0.f, 0.f, 0.f, 0.f};

        const char* sBc = (const char*)&sB[cur][0];
        #pragma unroll
        for (int kst = 0; kst < 4; kst++) {
            bf16x8 af[2], bfv;
            #pragma unroll
            for (int i = 0; i < 2; i++) {     // A = keys (n rows)
                int nr = wn*32 + i*16 + lm;
                af[i] = *(const bf16x8*)(sBc + nr*256 + ((((kst<<2) + kh) ^ (nr & 7)) << 4));
            }
            {                                 // B = h (b cols)
                int br = wm*16 + lm;
                bfv = *(const bf16x8*)((const char*)sA + br*256 + ((((kst<<2) + kh) ^ (br & 7)) << 4));
            }
            #pragma unroll
            for (int i = 0; i < 2; i++)
                acc[i] = __builtin_amdgcn_mfma_f32_16x16x32_bf16(af[i], bfv, acc[i], 0, 0, 0);
        }

        // compute this tile's packed bins (held in regs across the barrier)
        {
            const float q2v = q2s[bcol];
            #pragma unroll
            for (int i = 0; i < 2; i++) {
                int nl = wn*32 + i*16 + kh*4;
                float4 kq = *(const float4*)&k2s[cur][nl];
                unsigned pk = 0;
                #pragma unroll
                for (int rg = 0; rg < 4; rg++) {
                    float kv = (rg == 0) ? kq.x : (rg == 1) ? kq.y : (rg == 2) ? kq.z : kq.w;
                    float d2v = (q2v + kv) - 2.0f*acc[i][rg];
                    float dc = fminf(fmaxf(d2v, 16.0f), 4095.0f);
                    unsigned bin = (__float_as_uint(dc) >> 19) - 2096u;  // [0,127]
                    pk |= bin << (8*rg);
                }
                if (i == 0) pk_prev0 = pk; else pk_prev1 = pk;
            }
            n0_prev = n0;
        }

        // convert prefetched regs -> other buffer (vmcnt wait lands here,
        // after the MFMA phase covered the load latency)
        if (more) conv_store(lv, (char*)&sB[cur ^ 1][0], k2s[cur ^ 1], r, hh);
        __syncthreads();   // ds_writes visible; reads of sB[cur] retired
        cur ^= 1;
    }
    // final tile's store
    *(unsigned*)(bp_base + n0_prev + soff0) = pk_prev0;
    *(unsigned*)(bp_base + n0_prev + soff1) = pk_prev1;
}

// ============ Path A: fused hist + tau + collect + exact top-K ============
// One 512-thread block per (b,a) row. v7: 32 hist replicas with
// rep = lane&31 -> LDS bank = lane&31 (full 32-bank spread; the old
// rep = wave*4+lane&3 put each wave's 64 atomics on only 4 banks).
// Counts/margin/extraction logic identical to the proven kernels.
__global__ __launch_bounds__(512) void finish_kernel(
    const unsigned char* __restrict__ bins, const float* __restrict__ keys,
    const double* __restrict__ h64, const float* __restrict__ mem_values,
    float* __restrict__ out_values, double* __restrict__ val64)
{
    const int q = blockIdx.x;          // a*B_ + b (bins row)
    const int a = q >> 9, b = q & 511;
    const int p = b*A_ + a;            // output index
    const int tid = threadIdx.x;

    __shared__ unsigned hist_s[NBIN_A*32];
    __shared__ unsigned hc[NBIN_A];
    __shared__ double hd[DIM];
    __shared__ int    cidx[CAP_A];
    __shared__ double d2s[CAP_A];
    __shared__ float  vs[CAP_A];
    __shared__ double redv[8];
    __shared__ int    redi8[8];
    __shared__ double acc_w, acc_wv;
    __shared__ unsigned cnt_s;
    __shared__ int thr_s;

    for (int i = tid; i < NBIN_A*32; i += 512) hist_s[i] = 0;
    for (int i = tid; i < DIM; i += 512) hd[i] = h64[(size_t)b*DIM + i];
    if (tid == 0) { cnt_s = 0; acc_w = 0.0; acc_wv = 0.0; }
    __syncthreads();

    const uint4* row = (const uint4*)(bins + (size_t)q*C_);
    const int rep = tid & 31;          // bank = rep -> conflict-free spread
    // scan 1: histogram
    for (int ch = tid; ch < ROWCH; ch += 512) {
        uint4 v = row[ch];
        unsigned d[4] = {v.x, v.y, v.z, v.w};
        #pragma unroll
        for (int e = 0; e < 4; e++) {
            unsigned x = d[e];
            atomicAdd(&hist_s[((x      ) & 127u)*32 + rep], 1u);
            atomicAdd(&hist_s[((x >>  8) & 127u)*32 + rep], 1u);
            atomicAdd(&hist_s[((x >> 16) & 127u)*32 + rep], 1u);
            atomicAdd(&hist_s[((x >> 24) & 127u)*32 + rep], 1u);
        }
    }
    __syncthreads();
    if (tid < NBIN_A) {
        unsigned s = 0;
        #pragma unroll
        for (int r2 = 0; r2 < 32; r2++) s += hist_s[tid*32 + r2];
        hc[tid] = s;
    }
    __syncthreads();
    if (tid == 0) {
        unsigned cum = 0; int jsel = NBIN_A-1;
        for (int j = 0; j < NBIN_A; j++) { cum += hc[j]; if (cum >= K_) { jsel = j; break; } }
        unsigned c1 = cum + (jsel+1 < NBIN_A ? hc[jsel+1] : 0u);
        unsigned c2 = c1  + (jsel+2 < NBIN_A ? hc[jsel+2] : 0u);
        int jt = (c2 <= 768u) ? jsel+2 : jsel+1;   // capture margin
        if (jt > NBIN_A-1) jt = NBIN_A-1;
        thr_s = jt + 1;
    }
    __syncthreads();
    const unsigned thr  = (unsigned)thr_s;         // select bytes < thr
    const unsigned addv = (128u - thr) * 0x01010101u;
    // scan 2: collect candidates
    for (int ch = tid; ch < ROWCH; ch += 512) {
        uint4 v = row[ch];
        unsigned d[4] = {v.x, v.y, v.z, v.w};
        #pragma unroll
        for (int e = 0; e < 4; e++) {
            unsigned m = (d[e] + addv) & 0x80808080u;
            if (m != 0x80808080u) {
                #pragma unroll
                for (int by = 0; by < 4; by++) {
                    if (!((m >> (8*by + 7)) & 1u)) {
                        unsigned pos = atomicAdd(&cnt_s, 1u);
                        if (pos < CAP_A) cidx[pos] = ch*16 + e*4 + by;
                    }
                }
            }
        }
    }
    __syncthreads();
    int n = (int)cnt_s; if (n > CAP_A) n = CAP_A;

    // exact fp64 distances
    for (int i = tid; i < n; i += 512) {
        int c = cidx[i];
        const float4* kr = (const float4*)(keys + ((size_t)a*C_ + c)*DIM);
        double s0 = 0.0, s1 = 0.0;
        #pragma unroll 4
        for (int kq = 0; kq < 32; kq++) {
            float4 kv = kr[kq];
            double d0 = hd[4*kq+0] - (double)kv.x;
            double d1 = hd[4*kq+1] - (double)kv.y;
            double d2 = hd[4*kq+2] - (double)kv.z;
            double d3 = hd[4*kq+3] - (double)kv.w;
            s0 += d0*d0 + d1*d1; s1 += d2*d2 + d3*d3;
        }
        d2s[i] = s0 + s1;
        vs[i]  = mem_values[(size_t)a*C_ + c];
    }
    __syncthreads();

    // serial top-K extraction (shuffle butterfly, 2 barriers/iter)
    int kk = n < K_ ? n : K_;
    for (int t = 0; t < kk; t++) {
        double best = 1e300; int bi = -1;
        for (int i = tid; i < n; i += 512)
            if (d2s[i] < best) { best = d2s[i]; bi = i; }
        #pragma unroll
        for (int off = 32; off > 0; off >>= 1) {
            double ov = __shfl_xor(best, off, 64);
            int    oi = __shfl_xor(bi,   off, 64);
            if (ov < best) { best = ov; bi = oi; }
        }
        int wv = tid >> 6;
        if ((tid & 63) == 0) { redv[wv] = best; redi8[wv] = bi; }
        __syncthreads();
        if (tid == 0) {
            double bv = redv[0]; int wi = redi8[0];
            #pragma unroll
            for (int u = 1; u < 8; u++)
                if (redv[u] < bv) { bv = redv[u]; wi = redi8[u]; }
            double d = d2s[wi]; if (d < 0.0) d = 0.0;
            double wgt = 1.0 / (d + DELTA);
            acc_w += wgt; acc_wv += wgt * (double)vs[wi];
            d2s[wi] = 2e300;
        }
        __syncthreads();
    }
    if (tid == 0) {
        double v = acc_wv / acc_w;
        out_values[p] = (float)v;
        val64[p] = v;
    }
}

// ============ Path B (round-1 fallback) kernels ============
__global__ __launch_bounds__(256) void k2_kernel(const float* __restrict__ keys,
                                                 float* __restrict__ k2)
{
    int r = blockIdx.x*4 + (threadIdx.x >> 6);
    int lane = threadIdx.x & 63;
    float2 v = ((const float2*)keys)[(size_t)r*64 + lane];
    float s = v.x*v.x + v.y*v.y;
    #pragma unroll
    for (int off = 32; off > 0; off >>= 1) s += __shfl_down(s, off, 64);
    if (lane == 0) k2[r] = s;
}

template<int MODE>
__global__ __launch_bounds__(256) void pass_kernel(
    const float* __restrict__ keys, const float* __restrict__ h32,
    const float* __restrict__ q2,   const float* __restrict__ k2,
    unsigned* __restrict__ hist,    const float* __restrict__ tau,
    unsigned* __restrict__ cnt,     int* __restrict__ cand)
{
    const int bt = blockIdx.x;
    const int ch = blockIdx.y;
    const int a  = blockIdx.z;
    const int b0 = bt*BM_B;
    const int tid = threadIdx.x;
    const int tx = tid & 31, ty = tid >> 5;

    __shared__ float4 hs4[BM_B*33];
    __shared__ float4 ks4[BN_B*33];
    __shared__ float  q2s[BM_B];
    __shared__ float  taus[BM_B];
    __shared__ unsigned hist_s[MODE == 0 ? BM_B*NBIN_B : 1];

    #pragma unroll
    for (int q = 0; q < BM_B*32/256; q++) {
        int flat = q*256 + tid; int row = flat >> 5, kq = flat & 31;
        hs4[row*33 + kq] = ((const float4*)h32)[(size_t)(b0+row)*32 + kq];
    }
    if (tid < BM_B) {
        q2s[tid] = q2[b0+tid];
        if (MODE == 1) taus[tid] = tau[(b0+tid)*A_ + a];
    }
    if (MODE == 0) for (int i = tid; i < BM_B*NBIN_B; i += 256) hist_s[i] = 0;
    const float* __restrict__ k2g = k2 + (size_t)a*C_;

    for (int t = 0; t < TPC_B; t++) {
        int n0 = ch*CHUNK_B + t*BN_B;
        if (n0 >= C_) break;
        __syncthreads();
        #pragma unroll
        for (int q = 0; q < 16; q++) {
            int flat = q*256 + tid; int row = flat >> 5, kq = flat & 31;
            int nr = n0 + row; if (nr >= C_) nr = C_-1;
            ks4[row*33 + kq] = ((const float4*)keys)[((size_t)a*C_ + nr)*32 + kq];
        }
        __syncthreads();

        float acc[8][4];
        #pragma unroll
        for (int i = 0; i < 8; i++)
            #pragma unroll
            for (int j = 0; j < 4; j++) acc[i][j] = 0.0f;

        for (int kq = 0; kq < 32; kq++) {
            float4 hv[8], kv[4];
            #pragma unroll
            for (int i = 0; i < 8; i++) hv[i] = hs4[(ty*8+i)*33 + kq];
            #pragma unroll
            for (int j = 0; j < 4; j++) kv[j] = ks4[(j*32+tx)*33 + kq];
            #pragma unroll
            for (int i = 0; i < 8; i++)
                #pragma unroll
                for (int j = 0; j < 4; j++)
                    acc[i][j] += hv[i].x*kv[j].x + hv[i].y*kv[j].y
                               + hv[i].z*kv[j].z + hv[i].w*kv[j].w;
        }

        #pragma unroll
        for (int i = 0; i < 8; i++) {
            int bl = ty*8 + i;
            float q2b = q2s[bl];
            #pragma unroll
            for (int j = 0; j < 4; j++) {
                int n = n0 + j*32 + tx;
                if (n < C_) {
                    float d2f = fmaxf(q2b + k2g[n] - 2.0f*acc[i][j], 0.0f);
                    if (MODE == 0) {
                        int bin = (int)(__float_as_uint(d2f + 1.0f) >> 19) - 2032;
                        bin = bin < 0 ? 0 : (bin > NBIN_B-1 ? NBIN_B-1 : bin);
                        atomicAdd(&hist_s[bl*NBIN_B + bin], 1u);
                    } else {
                        if (d2f < taus[bl]) {
                            int p = (b0+bl)*A_ + a;
                            unsigned pos = atomicAdd(&cnt[p], 1u);
                            if (pos < CAP_B) cand[(size_t)p*CAP_B + pos] = n;
                        }
                    }
                }
            }
        }
    }
    if (MODE == 0) {
        __syncthreads();
        for (int i = tid; i < BM_B*NBIN_B; i += 256) {
            unsigned v = hist_s[i];
            if (v) {
                int bl = i / NBIN_B, bin = i % NBIN_B;
                atomicAdd(&hist[(size_t)((b0+bl)*A_ + a)*NBIN_B + bin], v);
            }
        }
    }
}

__global__ __launch_bounds__(256) void tauB_kernel(const unsigned* __restrict__ hist,
                                                   float* __restrict__ tau)
{
    int p = blockIdx.x*256 + threadIdx.x;
    if (p >= B_*A_) return;
    const unsigned* hp = hist + (size_t)p*NBIN_B;
    unsigned cum = 0; int jsel = NBIN_B-1;
    for (int j = 0; j < NBIN_B; j++) { cum += hp[j]; if (cum >= K_) { jsel = j; break; } }
    tau[p] = __uint_as_float((unsigned)(2034 + jsel) << 19) - 1.0f;
}

// ============ Path B: exact fp64 top-K + NEC weighted value ============
__global__ __launch_bounds__(256) void select_kernel(
    const float* __restrict__ keys, const double* __restrict__ h64,
    const float* __restrict__ mem_values,
    const unsigned* __restrict__ cnt, const int* __restrict__ cand,
    float* __restrict__ out_values, double* __restrict__ val64, int cap)
{
    int p = blockIdx.x; int b = p / A_, a = p % A_;
    int tid = threadIdx.x;
    __shared__ double hd[DIM];
    __shared__ double d2s[CAP_A];
    __shared__ float  vs[CAP_A];
    __shared__ double redv[4];
    __shared__ int    redi4[4];
    __shared__ double acc_w, acc_wv;

    for (int i = tid; i < DIM; i += 256) hd[i] = h64[(size_t)b*DIM + i];
    if (tid == 0) { acc_w = 0.0; acc_wv = 0.0; }
    __syncthreads();

    int n = (int)cnt[p]; if (n > cap) n = cap;
    for (int i = tid; i < n; i += 256) {
        int c = cand[(size_t)p*cap + i];
        const float4* kr = (const float4*)(keys + ((size_t)a*C_ + c)*DIM);
        double s0 = 0.0, s1 = 0.0;
        #pragma unroll 4
        for (int kq = 0; kq < 32; kq++) {
            float4 kv = kr[kq];
            double d0 = hd[4*kq+0] - (double)kv.x;
            double d1 = hd[4*kq+1] - (double)kv.y;
            double d2 = hd[4*kq+2] - (double)kv.z;
            double d3 = hd[4*kq+3] - (double)kv.w;
            s0 += d0*d0 + d1*d1; s1 += d2*d2 + d3*d3;
        }
        d2s[i] = s0 + s1;
        vs[i]  = mem_values[(size_t)a*C_ + c];
    }
    __syncthreads();

    int kk = n < K_ ? n : K_;
    for (int t = 0; t < kk; t++) {
        double best = 1e300; int bi = -1;
        for (int i = tid; i < n; i += 256)
            if (d2s[i] < best) { best = d2s[i]; bi = i; }
        #pragma unroll
        for (int off = 32; off > 0; off >>= 1) {
            double ov = __shfl_xor(best, off, 64);
            int    oi = __shfl_xor(bi,   off, 64);
            if (ov < best) { best = ov; bi = oi; }
        }
        int wv = tid >> 6;
        if ((tid & 63) == 0) { redv[wv] = best; redi4[wv] = bi; }
        __syncthreads();
        if (tid == 0) {
            double bv = redv[0]; int wi = redi4[0];
            if (redv[1] < bv) { bv = redv[1]; wi = redi4[1]; }
            if (redv[2] < bv) { bv = redv[2]; wi = redi4[2]; }
            if (redv[3] < bv) { bv = redv[3]; wi = redi4[3]; }
            double d = d2s[wi]; if (d < 0.0) d = 0.0;
            double wgt = 1.0 / (d + DELTA);
            acc_w += wgt; acc_wv += wgt * (double)vs[wi];
            d2s[wi] = 2e300;
        }
        __syncthreads();
    }
    if (tid == 0) {
        double v = acc_wv / acc_w;
        out_values[p] = (float)v;
        val64[p] = v;
    }
}

__global__ void argmax_kernel(const double* __restrict__ val64, float* __restrict__ out)
{
    int b = blockIdx.x*blockDim.x + threadIdx.x;
    if (b >= B_) return;
    double v0 = val64[b*A_+0], v1 = val64[b*A_+1], v2 = val64[b*A_+2];
    int bi = 0; double bv = v0;
    if (v1 > bv) { bv = v1; bi = 1; }
    if (v2 > bv) { bv = v2; bi = 2; }
    out[B_*A_ + b] = (float)bi;
}

// ============ host ============
extern "C" void kernel_launch(void* const* d_in, const int* in_sizes, int n_in,
                              void* d_out, int out_size, void* d_ws, size_t ws_size,
                              hipStream_t stream)
{
    const float* x    = (const float*)d_in[0];
    const float* W1   = (const float*)d_in[1];
    const float* b1   = (const float*)d_in[2];
    const float* W2   = (const float*)d_in[3];
    const float* b2   = (const float*)d_in[4];
    const float* W3   = (const float*)d_in[5];
    const float* b3   = (const float*)d_in[6];
    const float* W4   = (const float*)d_in[7];
    const float* b4   = (const float*)d_in[8];
    const float* keys = (const float*)d_in[9];
    const float* memv = (const float*)d_in[10];

    char* ws = (char*)d_ws;

    if (ws_size >= NEED_A) {
        // -------- Path A: MFMA gemm -> bins -> fused finish --------
        double*         h64  = (double*)        (ws + AOFF_H64);
        float*          h32  = (float*)         (ws + AOFF_H32);
        unsigned short* hbf  = (unsigned short*)(ws + AOFF_HBF);
        float*          q2   = (float*)         (ws + AOFF_Q2);
        double*         v64  = (double*)        (ws + AOFF_V64);
        unsigned char*  bins = (unsigned char*) (ws + AOFF_BINS);

        mlp_kernel<<<B_, 128, 0, stream>>>(x, W1, b1, W2, b2, W3, b3, W4, b4, h32, hbf, h64, q2);
        gemm3_kernel<<<dim3(NSEG3, 8, A_), 512, 0, stream>>>(keys, hbf, q2, bins);
        finish_kernel<<<B_*A_, 512, 0, stream>>>(bins, keys, h64, memv, (float*)d_out, v64);
        argmax_kernel<<<2, 256, 0, stream>>>(v64, (float*)d_out);
    } else {
        // -------- Path B: round-1 proven fp32 two-pass --------
        float*          h32  = (float*)         (ws + BOFF_H32);
        double*         h64  = (double*)        (ws + BOFF_H64);
        float*          q2   = (float*)         (ws + BOFF_Q2);
        float*          k2   = (float*)         (ws + BOFF_K2);
        unsigned*       hist = (unsigned*)      (ws + BOFF_HIST);
        float*          tau  = (float*)         (ws + BOFF_TAU);
        unsigned*       cnt  = (unsigned*)      (ws + BOFF_CNT);
        double*         v64  = (double*)        (ws + BOFF_V64);
        int*            cand = (int*)           (ws + BOFF_CAND);
        unsigned short* hbf  = (unsigned short*)(ws + BOFF_CAND); // scratch

        hipMemsetAsync(ws + BOFF_HIST, 0, (BOFF_CNT + B_*A_*4) - BOFF_HIST, stream);

        mlp_kernel<<<B_, 128, 0, stream>>>(x, W1, b1, W2, b2, W3, b3, W4, b4, h32, hbf, h64, q2);
        k2_kernel<<<(A_*C_)/4, 256, 0, stream>>>(keys, k2);
        pass_kernel<0><<<dim3(B_/BM_B, NCH_B, A_), 256, 0, stream>>>(keys, h32, q2, k2, hist, nullptr, nullptr, nullptr);
        tauB_kernel<<<(B_*A_ + 255)/256, 256, 0, stream>>>(hist, tau);
        pass_kernel<1><<<dim3(B_/BM_B, NCH_B, A_), 256, 0, stream>>>(keys, h32, q2, k2, nullptr, tau, cnt, cand);
        select_kernel<<<B_*A_, 256, 0, stream>>>(keys, h64, memv, cnt, cand, (float*)d_out, v64, CAP_B);
        argmax_kernel<<<2, 256, 0, stream>>>(v64, (float*)d_out);
    }
}

// Round 7
// 966.567 us; speedup vs baseline: 1.1359x; 1.1220x over previous
//
#include <hip/hip_runtime.h>
#include <hip/hip_bf16.h>
#include <math.h>

// ---------------- problem constants ----------------
#define B_    512
#define DIM   128
#define A_    3
#define C_    200000
#define K_    50
#define DELTA 1e-3

typedef __attribute__((ext_vector_type(8))) short bf16x8;
typedef __attribute__((ext_vector_type(4))) float f32x4;

// ---------------- Path A constants ----------------
#define NBIN_A 128          // 16 bins/octave over d2 in [16,4096)
#define CAP_A  1024
#define ROWCH  12500        // 16B chunks per row (200000/16)

// gemm4 geometry: each block owns ALL 512 b-rows (h fully in LDS) and a
// PRIVATE 800-key range -> keys read exactly once, zero inter-block reuse
// needed, blocks fully independent (no lockstep/co-residency fragility).
#define NBLK4  250          // key-chunks per a (250*800 = 200000 exact)
#define GT4    32           // keys per tile
#define GTPB4  25           // tiles per block (25*32 = 800)

// Path A ws offsets (bytes)
#define AOFF_H64   0u
#define AOFF_H32   524288u
#define AOFF_HBF   786432u
#define AOFF_Q2    917504u
#define AOFF_V64   1718272u
#define AOFF_BINS  8022016u
#define NEED_A     (8022016ull + 307200000ull)   // ~315.2 MB

// ---------------- Path B (round-1 fallback) constants ----------------
#define NBIN_B 192
#define CAP_B  768
#define BM_B   64
#define BN_B   128
#define TPC_B  16
#define CHUNK_B (TPC_B*BN_B)
#define NCH_B  ((C_ + CHUNK_B - 1)/CHUNK_B)

#define BOFF_H32   0u
#define BOFF_H64   262144u
#define BOFF_Q2    786432u
#define BOFF_K2    788480u
#define BOFF_HIST  3188480u
#define BOFF_TAU   4368128u
#define BOFF_CNT   4374272u
#define BOFF_V64   4380416u
#define BOFF_CAND  4392704u

static __device__ inline unsigned short f2bf(float x) {
    union { float f; unsigned u; } c; c.f = x;
    unsigned r = (c.u + 0x7FFFu + ((c.u >> 16) & 1u)) >> 16;
    return (unsigned short)r;
}
static __device__ inline unsigned pkbf(float a, float b) {
    __hip_bfloat162 t = __float22bfloat162_rn(make_float2(a, b));
    union { __hip_bfloat162 h; unsigned u; } cv; cv.h = t; return cv.u;
}

// ============ MLP encoder (fp64, matches np-f64 ref) ============
__global__ __launch_bounds__(128) void mlp_kernel(
    const float* __restrict__ x,
    const float* __restrict__ W1, const float* __restrict__ b1,
    const float* __restrict__ W2, const float* __restrict__ b2,
    const float* __restrict__ W3, const float* __restrict__ b3,
    const float* __restrict__ W4, const float* __restrict__ b4,
    float* __restrict__ h32, unsigned short* __restrict__ hbf,
    double* __restrict__ h64, float* __restrict__ q2)
{
    int b = blockIdx.x, t = threadIdx.x;
    __shared__ double s0[DIM], s1[DIM];
    double x0 = (double)x[b*2+0], x1 = (double)x[b*2+1];
    double h = x0*(double)W1[t] + x1*(double)W1[DIM+t] + (double)b1[t];
    s0[t] = h > 0.0 ? h : 0.0;
    __syncthreads();
    double acc = (double)b2[t];
    for (int k = 0; k < DIM; k++) acc += s0[k]*(double)W2[k*DIM+t];
    s1[t] = acc > 0.0 ? acc : 0.0;
    __syncthreads();
    acc = (double)b3[t];
    for (int k = 0; k < DIM; k++) acc += s1[k]*(double)W3[k*DIM+t];
    s0[t] = acc > 0.0 ? acc : 0.0;
    __syncthreads();
    acc = (double)b4[t];
    for (int k = 0; k < DIM; k++) acc += s0[k]*(double)W4[k*DIM+t];
    h64[b*DIM+t] = acc;
    float hf = (float)acc;
    h32[b*DIM+t] = hf;
    hbf[b*DIM+t] = f2bf(hf);
    s1[t] = acc*acc;
    __syncthreads();
    for (int s = 64; s > 0; s >>= 1) { if (t < s) s1[t] += s1[t+s]; __syncthreads(); }
    if (t == 0) q2[b] = (float)s1[0];
}

// ---- gemm4 helpers ----
// 32 rows x 16 chunks: thread (r = tid>>4, hh = tid&15) loads 8 floats
static __device__ inline void load2(float4 lv[2], const float* __restrict__ ka,
                                    int nrow, int hh) {
    const float4* gp = (const float4*)(ka + (size_t)nrow*DIM) + hh*2;
    lv[0] = gp[0]; lv[1] = gp[1];
}
static __device__ inline void conv_store32(const float4 lv[2], char* sBn,
                                           float* k2n, int r, int hh) {
    float4 v0 = lv[0], v1 = lv[1];
    float ss = v0.x*v0.x + v0.y*v0.y + v0.z*v0.z + v0.w*v0.w
             + v1.x*v1.x + v1.y*v1.y + v1.z*v1.z + v1.w*v1.w;
    int4 pk;
    pk.x = (int)pkbf(v0.x, v0.y); pk.y = (int)pkbf(v0.z, v0.w);
    pk.z = (int)pkbf(v1.x, v1.y); pk.w = (int)pkbf(v1.z, v1.w);
    *(int4*)(sBn + r*256 + ((hh ^ (r & 7)) << 4)) = pk;
    ss += __shfl_xor(ss, 1, 64);
    ss += __shfl_xor(ss, 2, 64);
    ss += __shfl_xor(ss, 4, 64);
    ss += __shfl_xor(ss, 8, 64);
    if (hh == 0) k2n[r] = ss;
}

// ============ Path A: bf16 MFMA distance GEMM -> u8 log-bins ============
// v8: full-b blocks. sA holds ALL 512 h-rows (128 KB). Per 32-key tile each
// wave does 32 MFMAs (2 n-frags x 4 b-frags x K=128) -- 4x the compute per
// staging barrier of v7, so the single-deep pipeline actually hides HBM
// latency. Deferred bins stores (cross-barrier) as before. Keys read once.
__global__ __launch_bounds__(512, 1) void gemm4_kernel(
    const float* __restrict__ keys, const unsigned short* __restrict__ hbf,
    const float* __restrict__ q2, unsigned char* __restrict__ bins)
{
    const int blk = blockIdx.x, a = blockIdx.y;
    const int tid = threadIdx.x;
    const int lane = tid & 63, w = tid >> 6;
    const int lm = lane & 15, kh = lane >> 4;

    __shared__ __align__(16) short sA[512*128];   // h 512x128 bf16, swizzled (128 KB)
    __shared__ __align__(16) short sB[2][32*128]; // keys 32x128 bf16 dbuf (16 KB)
    __shared__ float q2s[512];
    __shared__ float k2s[2][32];

    // stage sA: 8192 int4 chunks, 16 per thread, coalesced; XOR-swizzled
    #pragma unroll
    for (int u = 0; u < 16; u++) {
        int idx = u*512 + tid;
        int rr = idx >> 4, cc = idx & 15;
        int4 gv = ((const int4*)hbf)[rr*16 + cc];
        *(int4*)((char*)sA + rr*256 + ((cc ^ (rr & 7)) << 4)) = gv;
    }
    q2s[tid] = q2[tid];

    const int r = tid >> 4, hh = tid & 15;   // 32 rows x 16 chunks
    const float* ka = keys + (size_t)a*C_*DIM;
    const int nbase = blk*(GT4*GTPB4);

    float4 lv[2];
    load2(lv, ka, nbase + r, hh);
    conv_store32(lv, (char*)&sB[0][0], k2s[0], r, hh);
    __syncthreads();   // sA + q2s + tile0 staged

    // loop-invariant store pointers: row = b (bcol), col = n
    unsigned char* rp0; unsigned char* rp1; unsigned char* rp2; unsigned char* rp3;
    {
        unsigned char* base = bins + (size_t)(a*B_)*C_ + kh*4;
        rp0 = base + (size_t)(w*64 +  0 + lm)*C_;
        rp1 = base + (size_t)(w*64 + 16 + lm)*C_;
        rp2 = base + (size_t)(w*64 + 32 + lm)*C_;
        rp3 = base + (size_t)(w*64 + 48 + lm)*C_;
    }

    unsigned pkp[8];   // deferred bins (j=0..3 x i=0..1), fully unrolled idx
    #pragma unroll
    for (int u = 0; u < 8; u++) pkp[u] = 0;
    int n0_prev = 0;

    int cur = 0;
    for (int t = 0; t < GTPB4; t++) {
        const int n0 = nbase + t*GT4;
        const bool more = (t + 1 < GTPB4);

        // issue next tile's fp32 loads first (oldest in queue; fly under MFMA)
        if (more) load2(lv, ka, n0 + GT4 + r, hh);
        // deferred store of previous tile's bins (retire during this tile)
        if (t > 0) {
            *(unsigned*)(rp0 + n0_prev     ) = pkp[0];
            *(unsigned*)(rp0 + n0_prev + 16) = pkp[1];
            *(unsigned*)(rp1 + n0_prev     ) = pkp[2];
            *(unsigned*)(rp1 + n0_prev + 16) = pkp[3];
            *(unsigned*)(rp2 + n0_prev     ) = pkp[4];
            *(unsigned*)(rp2 + n0_prev + 16) = pkp[5];
            *(unsigned*)(rp3 + n0_prev     ) = pkp[6];
            *(unsigned*)(rp3 + n0_prev + 16) = pkp[7];
        }

        f32x4 acc[2][4];
        #pragma unroll
        for (int i = 0; i < 2; i++)
            #pragma unroll
            for (int j = 0; j < 4; j++) acc[i][j] = (f32x4){0.f, 0.f, 0.f, 0.f};

        const char* sBc = (const char*)&sB[cur][0];
        #pragma unroll
        for (int kst = 0; kst < 4; kst++) {
            bf16x8 af[2], bfv[4];
            #pragma unroll
            for (int i = 0; i < 2; i++) {     // A = keys (n rows 0..31)
                int nr = i*16 + lm;
                af[i] = *(const bf16x8*)(sBc + nr*256 + ((((kst<<2) + kh) ^ (nr & 7)) << 4));
            }
            #pragma unroll
            for (int j = 0; j < 4; j++) {     // B = h (wave's 64 b cols)
                int br = w*64 + j*16 + lm;
                bfv[j] = *(const bf16x8*)((const char*)sA + br*256 + ((((kst<<2) + kh) ^ (br & 7)) << 4));
            }
            #pragma unroll
            for (int i = 0; i < 2; i++)
                #pragma unroll
                for (int j = 0; j < 4; j++)
                    acc[i][j] = __builtin_amdgcn_mfma_f32_16x16x32_bf16(af[i], bfv[j], acc[i][j], 0, 0, 0);
        }

        // compute this tile's packed bins (held in regs across the barrier)
        {
            float4 kq0 = *(const float4*)&k2s[cur][kh*4];        // i=0 quad
            float4 kq1 = *(const float4*)&k2s[cur][16 + kh*4];   // i=1 quad
            #pragma unroll
            for (int j = 0; j < 4; j++) {
                float q2v = q2s[w*64 + j*16 + lm];
                #pragma unroll
                for (int i = 0; i < 2; i++) {
                    float4 kq = (i == 0) ? kq0 : kq1;
                    unsigned pk = 0;
                    #pragma unroll
                    for (int rg = 0; rg < 4; rg++) {
                        float kv = (rg == 0) ? kq.x : (rg == 1) ? kq.y : (rg == 2) ? kq.z : kq.w;
                        float d2v = (q2v + kv) - 2.0f*acc[i][j][rg];
                        float dc = fminf(fmaxf(d2v, 16.0f), 4095.0f);
                        unsigned bin = (__float_as_uint(dc) >> 19) - 2096u;  // [0,127]
                        pk |= bin << (8*rg);
                    }
                    pkp[j*2 + i] = pk;
                }
            }
            n0_prev = n0;
        }

        // convert prefetched regs -> other buffer (vmcnt wait lands here,
        // after the MFMA+epilogue phase covered the load latency)
        if (more) conv_store32(lv, (char*)&sB[cur ^ 1][0], k2s[cur ^ 1], r, hh);
        __syncthreads();   // ds_writes visible; reads of sB[cur] retired
        cur ^= 1;
    }
    // final tile's stores
    *(unsigned*)(rp0 + n0_prev     ) = pkp[0];
    *(unsigned*)(rp0 + n0_prev + 16) = pkp[1];
    *(unsigned*)(rp1 + n0_prev     ) = pkp[2];
    *(unsigned*)(rp1 + n0_prev + 16) = pkp[3];
    *(unsigned*)(rp2 + n0_prev     ) = pkp[4];
    *(unsigned*)(rp2 + n0_prev + 16) = pkp[5];
    *(unsigned*)(rp3 + n0_prev     ) = pkp[6];
    *(unsigned*)(rp3 + n0_prev + 16) = pkp[7];
}

// ============ Path A: fused hist + tau + collect + exact top-K ============
// One 512-thread block per (b,a) row. 32 hist replicas, rep = lane&31
// -> bank = lane&31 (full 32-bank spread). Counts/margin/extraction logic
// identical to the proven kernels.
__global__ __launch_bounds__(512) void finish_kernel(
    const unsigned char* __restrict__ bins, const float* __restrict__ keys,
    const double* __restrict__ h64, const float* __restrict__ mem_values,
    float* __restrict__ out_values, double* __restrict__ val64)
{
    const int q = blockIdx.x;          // a*B_ + b (bins row)
    const int a = q >> 9, b = q & 511;
    const int p = b*A_ + a;            // output index
    const int tid = threadIdx.x;

    __shared__ unsigned hist_s[NBIN_A*32];
    __shared__ unsigned hc[NBIN_A];
    __shared__ double hd[DIM];
    __shared__ int    cidx[CAP_A];
    __shared__ double d2s[CAP_A];
    __shared__ float  vs[CAP_A];
    __shared__ double redv[8];
    __shared__ int    redi8[8];
    __shared__ double acc_w, acc_wv;
    __shared__ unsigned cnt_s;
    __shared__ int thr_s;

    for (int i = tid; i < NBIN_A*32; i += 512) hist_s[i] = 0;
    for (int i = tid; i < DIM; i += 512) hd[i] = h64[(size_t)b*DIM + i];
    if (tid == 0) { cnt_s = 0; acc_w = 0.0; acc_wv = 0.0; }
    __syncthreads();

    const uint4* row = (const uint4*)(bins + (size_t)q*C_);
    const int rep = tid & 31;          // bank = rep -> conflict-free spread
    // scan 1: histogram
    for (int ch = tid; ch < ROWCH; ch += 512) {
        uint4 v = row[ch];
        unsigned d[4] = {v.x, v.y, v.z, v.w};
        #pragma unroll
        for (int e = 0; e < 4; e++) {
            unsigned x = d[e];
            atomicAdd(&hist_s[((x      ) & 127u)*32 + rep], 1u);
            atomicAdd(&hist_s[((x >>  8) & 127u)*32 + rep], 1u);
            atomicAdd(&hist_s[((x >> 16) & 127u)*32 + rep], 1u);
            atomicAdd(&hist_s[((x >> 24) & 127u)*32 + rep], 1u);
        }
    }
    __syncthreads();
    if (tid < NBIN_A) {
        unsigned s = 0;
        #pragma unroll
        for (int r2 = 0; r2 < 32; r2++) s += hist_s[tid*32 + r2];
        hc[tid] = s;
    }
    __syncthreads();
    if (tid == 0) {
        unsigned cum = 0; int jsel = NBIN_A-1;
        for (int j = 0; j < NBIN_A; j++) { cum += hc[j]; if (cum >= K_) { jsel = j; break; } }
        unsigned c1 = cum + (jsel+1 < NBIN_A ? hc[jsel+1] : 0u);
        unsigned c2 = c1  + (jsel+2 < NBIN_A ? hc[jsel+2] : 0u);
        int jt = (c2 <= 768u) ? jsel+2 : jsel+1;   // capture margin
        if (jt > NBIN_A-1) jt = NBIN_A-1;
        thr_s = jt + 1;
    }
    __syncthreads();
    const unsigned thr  = (unsigned)thr_s;         // select bytes < thr
    const unsigned addv = (128u - thr) * 0x01010101u;
    // scan 2: collect candidates
    for (int ch = tid; ch < ROWCH; ch += 512) {
        uint4 v = row[ch];
        unsigned d[4] = {v.x, v.y, v.z, v.w};
        #pragma unroll
        for (int e = 0; e < 4; e++) {
            unsigned m = (d[e] + addv) & 0x80808080u;
            if (m != 0x80808080u) {
                #pragma unroll
                for (int by = 0; by < 4; by++) {
                    if (!((m >> (8*by + 7)) & 1u)) {
                        unsigned pos = atomicAdd(&cnt_s, 1u);
                        if (pos < CAP_A) cidx[pos] = ch*16 + e*4 + by;
                    }
                }
            }
        }
    }
    __syncthreads();
    int n = (int)cnt_s; if (n > CAP_A) n = CAP_A;

    // exact fp64 distances
    for (int i = tid; i < n; i += 512) {
        int c = cidx[i];
        const float4* kr = (const float4*)(keys + ((size_t)a*C_ + c)*DIM);
        double s0 = 0.0, s1 = 0.0;
        #pragma unroll 4
        for (int kq = 0; kq < 32; kq++) {
            float4 kv = kr[kq];
            double d0 = hd[4*kq+0] - (double)kv.x;
            double d1 = hd[4*kq+1] - (double)kv.y;
            double d2 = hd[4*kq+2] - (double)kv.z;
            double d3 = hd[4*kq+3] - (double)kv.w;
            s0 += d0*d0 + d1*d1; s1 += d2*d2 + d3*d3;
        }
        d2s[i] = s0 + s1;
        vs[i]  = mem_values[(size_t)a*C_ + c];
    }
    __syncthreads();

    // serial top-K extraction (shuffle butterfly, 2 barriers/iter)
    int kk = n < K_ ? n : K_;
    for (int t = 0; t < kk; t++) {
        double best = 1e300; int bi = -1;
        for (int i = tid; i < n; i += 512)
            if (d2s[i] < best) { best = d2s[i]; bi = i; }
        #pragma unroll
        for (int off = 32; off > 0; off >>= 1) {
            double ov = __shfl_xor(best, off, 64);
            int    oi = __shfl_xor(bi,   off, 64);
            if (ov < best) { best = ov; bi = oi; }
        }
        int wv = tid >> 6;
        if ((tid & 63) == 0) { redv[wv] = best; redi8[wv] = bi; }
        __syncthreads();
        if (tid == 0) {
            double bv = redv[0]; int wi = redi8[0];
            #pragma unroll
            for (int u = 1; u < 8; u++)
                if (redv[u] < bv) { bv = redv[u]; wi = redi8[u]; }
            double d = d2s[wi]; if (d < 0.0) d = 0.0;
            double wgt = 1.0 / (d + DELTA);
            acc_w += wgt; acc_wv += wgt * (double)vs[wi];
            d2s[wi] = 2e300;
        }
        __syncthreads();
    }
    if (tid == 0) {
        double v = acc_wv / acc_w;
        out_values[p] = (float)v;
        val64[p] = v;
    }
}

// ============ Path B (round-1 fallback) kernels ============
__global__ __launch_bounds__(256) void k2_kernel(const float* __restrict__ keys,
                                                 float* __restrict__ k2)
{
    int r = blockIdx.x*4 + (threadIdx.x >> 6);
    int lane = threadIdx.x & 63;
    float2 v = ((const float2*)keys)[(size_t)r*64 + lane];
    float s = v.x*v.x + v.y*v.y;
    #pragma unroll
    for (int off = 32; off > 0; off >>= 1) s += __shfl_down(s, off, 64);
    if (lane == 0) k2[r] = s;
}

template<int MODE>
__global__ __launch_bounds__(256) void pass_kernel(
    const float* __restrict__ keys, const float* __restrict__ h32,
    const float* __restrict__ q2,   const float* __restrict__ k2,
    unsigned* __restrict__ hist,    const float* __restrict__ tau,
    unsigned* __restrict__ cnt,     int* __restrict__ cand)
{
    const int bt = blockIdx.x;
    const int ch = blockIdx.y;
    const int a  = blockIdx.z;
    const int b0 = bt*BM_B;
    const int tid = threadIdx.x;
    const int tx = tid & 31, ty = tid >> 5;

    __shared__ float4 hs4[BM_B*33];
    __shared__ float4 ks4[BN_B*33];
    __shared__ float  q2s[BM_B];
    __shared__ float  taus[BM_B];
    __shared__ unsigned hist_s[MODE == 0 ? BM_B*NBIN_B : 1];

    #pragma unroll
    for (int q = 0; q < BM_B*32/256; q++) {
        int flat = q*256 + tid; int row = flat >> 5, kq = flat & 31;
        hs4[row*33 + kq] = ((const float4*)h32)[(size_t)(b0+row)*32 + kq];
    }
    if (tid < BM_B) {
        q2s[tid] = q2[b0+tid];
        if (MODE == 1) taus[tid] = tau[(b0+tid)*A_ + a];
    }
    if (MODE == 0) for (int i = tid; i < BM_B*NBIN_B; i += 256) hist_s[i] = 0;
    const float* __restrict__ k2g = k2 + (size_t)a*C_;

    for (int t = 0; t < TPC_B; t++) {
        int n0 = ch*CHUNK_B + t*BN_B;
        if (n0 >= C_) break;
        __syncthreads();
        #pragma unroll
        for (int q = 0; q < 16; q++) {
            int flat = q*256 + tid; int row = flat >> 5, kq = flat & 31;
            int nr = n0 + row; if (nr >= C_) nr = C_-1;
            ks4[row*33 + kq] = ((const float4*)keys)[((size_t)a*C_ + nr)*32 + kq];
        }
        __syncthreads();

        float acc[8][4];
        #pragma unroll
        for (int i = 0; i < 8; i++)
            #pragma unroll
            for (int j = 0; j < 4; j++) acc[i][j] = 0.0f;

        for (int kq = 0; kq < 32; kq++) {
            float4 hv[8], kv[4];
            #pragma unroll
            for (int i = 0; i < 8; i++) hv[i] = hs4[(ty*8+i)*33 + kq];
            #pragma unroll
            for (int j = 0; j < 4; j++) kv[j] = ks4[(j*32+tx)*33 + kq];
            #pragma unroll
            for (int i = 0; i < 8; i++)
                #pragma unroll
                for (int j = 0; j < 4; j++)
                    acc[i][j] += hv[i].x*kv[j].x + hv[i].y*kv[j].y
                               + hv[i].z*kv[j].z + hv[i].w*kv[j].w;
        }

        #pragma unroll
        for (int i = 0; i < 8; i++) {
            int bl = ty*8 + i;
            float q2b = q2s[bl];
            #pragma unroll
            for (int j = 0; j < 4; j++) {
                int n = n0 + j*32 + tx;
                if (n < C_) {
                    float d2f = fmaxf(q2b + k2g[n] - 2.0f*acc[i][j], 0.0f);
                    if (MODE == 0) {
                        int bin = (int)(__float_as_uint(d2f + 1.0f) >> 19) - 2032;
                        bin = bin < 0 ? 0 : (bin > NBIN_B-1 ? NBIN_B-1 : bin);
                        atomicAdd(&hist_s[bl*NBIN_B + bin], 1u);
                    } else {
                        if (d2f < taus[bl]) {
                            int p = (b0+bl)*A_ + a;
                            unsigned pos = atomicAdd(&cnt[p], 1u);
                            if (pos < CAP_B) cand[(size_t)p*CAP_B + pos] = n;
                        }
                    }
                }
            }
        }
    }
    if (MODE == 0) {
        __syncthreads();
        for (int i = tid; i < BM_B*NBIN_B; i += 256) {
            unsigned v = hist_s[i];
            if (v) {
                int bl = i / NBIN_B, bin = i % NBIN_B;
                atomicAdd(&hist[(size_t)((b0+bl)*A_ + a)*NBIN_B + bin], v);
            }
        }
    }
}

__global__ __launch_bounds__(256) void tauB_kernel(const unsigned* __restrict__ hist,
                                                   float* __restrict__ tau)
{
    int p = blockIdx.x*256 + threadIdx.x;
    if (p >= B_*A_) return;
    const unsigned* hp = hist + (size_t)p*NBIN_B;
    unsigned cum = 0; int jsel = NBIN_B-1;
    for (int j = 0; j < NBIN_B; j++) { cum += hp[j]; if (cum >= K_) { jsel = j; break; } }
    tau[p] = __uint_as_float((unsigned)(2034 + jsel) << 19) - 1.0f;
}

// ============ Path B: exact fp64 top-K + NEC weighted value ============
__global__ __launch_bounds__(256) void select_kernel(
    const float* __restrict__ keys, const double* __restrict__ h64,
    const float* __restrict__ mem_values,
    const unsigned* __restrict__ cnt, const int* __restrict__ cand,
    float* __restrict__ out_values, double* __restrict__ val64, int cap)
{
    int p = blockIdx.x; int b = p / A_, a = p % A_;
    int tid = threadIdx.x;
    __shared__ double hd[DIM];
    __shared__ double d2s[CAP_A];
    __shared__ float  vs[CAP_A];
    __shared__ double redv[4];
    __shared__ int    redi4[4];
    __shared__ double acc_w, acc_wv;

    for (int i = tid; i < DIM; i += 256) hd[i] = h64[(size_t)b*DIM + i];
    if (tid == 0) { acc_w = 0.0; acc_wv = 0.0; }
    __syncthreads();

    int n = (int)cnt[p]; if (n > cap) n = cap;
    for (int i = tid; i < n; i += 256) {
        int c = cand[(size_t)p*cap + i];
        const float4* kr = (const float4*)(keys + ((size_t)a*C_ + c)*DIM);
        double s0 = 0.0, s1 = 0.0;
        #pragma unroll 4
        for (int kq = 0; kq < 32; kq++) {
            float4 kv = kr[kq];
            double d0 = hd[4*kq+0] - (double)kv.x;
            double d1 = hd[4*kq+1] - (double)kv.y;
            double d2 = hd[4*kq+2] - (double)kv.z;
            double d3 = hd[4*kq+3] - (double)kv.w;
            s0 += d0*d0 + d1*d1; s1 += d2*d2 + d3*d3;
        }
        d2s[i] = s0 + s1;
        vs[i]  = mem_values[(size_t)a*C_ + c];
    }
    __syncthreads();

    int kk = n < K_ ? n : K_;
    for (int t = 0; t < kk; t++) {
        double best = 1e300; int bi = -1;
        for (int i = tid; i < n; i += 256)
            if (d2s[i] < best) { best = d2s[i]; bi = i; }
        #pragma unroll
        for (int off = 32; off > 0; off >>= 1) {
            double ov = __shfl_xor(best, off, 64);
            int    oi = __shfl_xor(bi,   off, 64);
            if (ov < best) { best = ov; bi = oi; }
        }
        int wv = tid >> 6;
        if ((tid & 63) == 0) { redv[wv] = best; redi4[wv] = bi; }
        __syncthreads();
        if (tid == 0) {
            double bv = redv[0]; int wi = redi4[0];
            if (redv[1] < bv) { bv = redv[1]; wi = redi4[1]; }
            if (redv[2] < bv) { bv = redv[2]; wi = redi4[2]; }
            if (redv[3] < bv) { bv = redv[3]; wi = redi4[3]; }
            double d = d2s[wi]; if (d < 0.0) d = 0.0;
            double wgt = 1.0 / (d + DELTA);
            acc_w += wgt; acc_wv += wgt * (double)vs[wi];
            d2s[wi] = 2e300;
        }
        __syncthreads();
    }
    if (tid == 0) {
        double v = acc_wv / acc_w;
        out_values[p] = (float)v;
        val64[p] = v;
    }
}

__global__ void argmax_kernel(const double* __restrict__ val64, float* __restrict__ out)
{
    int b = blockIdx.x*blockDim.x + threadIdx.x;
    if (b >= B_) return;
    double v0 = val64[b*A_+0], v1 = val64[b*A_+1], v2 = val64[b*A_+2];
    int bi = 0; double bv = v0;
    if (v1 > bv) { bv = v1; bi = 1; }
    if (v2 > bv) { bv = v2; bi = 2; }
    out[B_*A_ + b] = (float)bi;
}

// ============ host ============
extern "C" void kernel_launch(void* const* d_in, const int* in_sizes, int n_in,
                              void* d_out, int out_size, void* d_ws, size_t ws_size,
                              hipStream_t stream)
{
    const float* x    = (const float*)d_in[0];
    const float* W1   = (const float*)d_in[1];
    const float* b1   = (const float*)d_in[2];
    const float* W2   = (const float*)d_in[3];
    const float* b2   = (const float*)d_in[4];
    const float* W3   = (const float*)d_in[5];
    const float* b3   = (const float*)d_in[6];
    const float* W4   = (const float*)d_in[7];
    const float* b4   = (const float*)d_in[8];
    const float* keys = (const float*)d_in[9];
    const float* memv = (const float*)d_in[10];

    char* ws = (char*)d_ws;

    if (ws_size >= NEED_A) {
        // -------- Path A: MFMA gemm -> bins -> fused finish --------
        double*         h64  = (double*)        (ws + AOFF_H64);
        float*          h32  = (float*)         (ws + AOFF_H32);
        unsigned short* hbf  = (unsigned short*)(ws + AOFF_HBF);
        float*          q2   = (float*)         (ws + AOFF_Q2);
        double*         v64  = (double*)        (ws + AOFF_V64);
        unsigned char*  bins = (unsigned char*) (ws + AOFF_BINS);

        mlp_kernel<<<B_, 128, 0, stream>>>(x, W1, b1, W2, b2, W3, b3, W4, b4, h32, hbf, h64, q2);
        gemm4_kernel<<<dim3(NBLK4, A_), 512, 0, stream>>>(keys, hbf, q2, bins);
        finish_kernel<<<B_*A_, 512, 0, stream>>>(bins, keys, h64, memv, (float*)d_out, v64);
        argmax_kernel<<<2, 256, 0, stream>>>(v64, (float*)d_out);
    } else {
        // -------- Path B: round-1 proven fp32 two-pass --------
        float*          h32  = (float*)         (ws + BOFF_H32);
        double*         h64  = (double*)        (ws + BOFF_H64);
        float*          q2   = (float*)         (ws + BOFF_Q2);
        float*          k2   = (float*)         (ws + BOFF_K2);
        unsigned*       hist = (unsigned*)      (ws + BOFF_HIST);
        float*          tau  = (float*)         (ws + BOFF_TAU);
        unsigned*       cnt  = (unsigned*)      (ws + BOFF_CNT);
        double*         v64  = (double*)        (ws + BOFF_V64);
        int*            cand = (int*)           (ws + BOFF_CAND);
        unsigned short* hbf  = (unsigned short*)(ws + BOFF_CAND); // scratch

        hipMemsetAsync(ws + BOFF_HIST, 0, (BOFF_CNT + B_*A_*4) - BOFF_HIST, stream);

        mlp_kernel<<<B_, 128, 0, stream>>>(x, W1, b1, W2, b2, W3, b3, W4, b4, h32, hbf, h64, q2);
        k2_kernel<<<(A_*C_)/4, 256, 0, stream>>>(keys, k2);
        pass_kernel<0><<<dim3(B_/BM_B, NCH_B, A_), 256, 0, stream>>>(keys, h32, q2, k2, hist, nullptr, nullptr, nullptr);
        tauB_kernel<<<(B_*A_ + 255)/256, 256, 0, stream>>>(hist, tau);
        pass_kernel<1><<<dim3(B_/BM_B, NCH_B, A_), 256, 0, stream>>>(keys, h32, q2, k2, nullptr, tau, cnt, cand);
        select_kernel<<<B_*A_, 256, 0, stream>>>(keys, h64, memv, cnt, cand, (float*)d_out, v64, CAP_B);
        argmax_kernel<<<2, 256, 0, stream>>>(v64, (float*)d_out);
    }
}

// Round 8
// 945.866 us; speedup vs baseline: 1.1607x; 1.0219x over previous
//
#include <hip/hip_runtime.h>
#include <hip/hip_bf16.h>
#include <math.h>

// ---------------- problem constants ----------------
#define B_    512
#define DIM   128
#define A_    3
#define C_    200000
#define K_    50
#define DELTA 1e-3

typedef __attribute__((ext_vector_type(8))) short bf16x8;
typedef __attribute__((ext_vector_type(4))) float f32x4;

// ---------------- Path A constants ----------------
#define NBIN_A 128          // 16 bins/octave over d2 in [16,4096)
#define CAP_A  1024
#define ROWCH  12500        // 16B chunks per row (200000/16)

// gemm4 geometry: each block owns ALL 512 b-rows (h fully in LDS) and a
// PRIVATE 800-key range -> keys read exactly once, zero inter-block reuse
// needed, blocks fully independent (no lockstep/co-residency fragility).
#define NBLK4  250          // key-chunks per a (250*800 = 200000 exact)
#define GT4    32           // keys per tile
#define GTPB4  25           // tiles per block (25*32 = 800)

// Path A ws offsets (bytes)
#define AOFF_H64   0u
#define AOFF_H32   524288u
#define AOFF_HBF   786432u
#define AOFF_Q2    917504u
#define AOFF_V64   1718272u
#define AOFF_BINS  8022016u
#define NEED_A     (8022016ull + 307200000ull)   // ~315.2 MB

// ---------------- Path B (round-1 fallback) constants ----------------
#define NBIN_B 192
#define CAP_B  768
#define BM_B   64
#define BN_B   128
#define TPC_B  16
#define CHUNK_B (TPC_B*BN_B)
#define NCH_B  ((C_ + CHUNK_B - 1)/CHUNK_B)

#define BOFF_H32   0u
#define BOFF_H64   262144u
#define BOFF_Q2    786432u
#define BOFF_K2    788480u
#define BOFF_HIST  3188480u
#define BOFF_TAU   4368128u
#define BOFF_CNT   4374272u
#define BOFF_V64   4380416u
#define BOFF_CAND  4392704u

static __device__ inline unsigned short f2bf(float x) {
    union { float f; unsigned u; } c; c.f = x;
    unsigned r = (c.u + 0x7FFFu + ((c.u >> 16) & 1u)) >> 16;
    return (unsigned short)r;
}
static __device__ inline unsigned pkbf(float a, float b) {
    __hip_bfloat162 t = __float22bfloat162_rn(make_float2(a, b));
    union { __hip_bfloat162 h; unsigned u; } cv; cv.h = t; return cv.u;
}

// ============ MLP encoder (fp64, matches np-f64 ref) ============
__global__ __launch_bounds__(128) void mlp_kernel(
    const float* __restrict__ x,
    const float* __restrict__ W1, const float* __restrict__ b1,
    const float* __restrict__ W2, const float* __restrict__ b2,
    const float* __restrict__ W3, const float* __restrict__ b3,
    const float* __restrict__ W4, const float* __restrict__ b4,
    float* __restrict__ h32, unsigned short* __restrict__ hbf,
    double* __restrict__ h64, float* __restrict__ q2)
{
    int b = blockIdx.x, t = threadIdx.x;
    __shared__ double s0[DIM], s1[DIM];
    double x0 = (double)x[b*2+0], x1 = (double)x[b*2+1];
    double h = x0*(double)W1[t] + x1*(double)W1[DIM+t] + (double)b1[t];
    s0[t] = h > 0.0 ? h : 0.0;
    __syncthreads();
    double acc = (double)b2[t];
    for (int k = 0; k < DIM; k++) acc += s0[k]*(double)W2[k*DIM+t];
    s1[t] = acc > 0.0 ? acc : 0.0;
    __syncthreads();
    acc = (double)b3[t];
    for (int k = 0; k < DIM; k++) acc += s1[k]*(double)W3[k*DIM+t];
    s0[t] = acc > 0.0 ? acc : 0.0;
    __syncthreads();
    acc = (double)b4[t];
    for (int k = 0; k < DIM; k++) acc += s0[k]*(double)W4[k*DIM+t];
    h64[b*DIM+t] = acc;
    float hf = (float)acc;
    h32[b*DIM+t] = hf;
    hbf[b*DIM+t] = f2bf(hf);
    s1[t] = acc*acc;
    __syncthreads();
    for (int s = 64; s > 0; s >>= 1) { if (t < s) s1[t] += s1[t+s]; __syncthreads(); }
    if (t == 0) q2[b] = (float)s1[0];
}

// ---- gemm4 helpers ----
// 32 rows x 16 chunks: thread (r = tid>>4, hh = tid&15) loads 8 floats
static __device__ inline void load2(float4 lv[2], const float* __restrict__ ka,
                                    int nrow, int hh) {
    const float4* gp = (const float4*)(ka + (size_t)nrow*DIM) + hh*2;
    lv[0] = gp[0]; lv[1] = gp[1];
}
static __device__ inline void conv_store32(const float4 lv[2], char* sBn,
                                           float* k2n, int r, int hh) {
    float4 v0 = lv[0], v1 = lv[1];
    float ss = v0.x*v0.x + v0.y*v0.y + v0.z*v0.z + v0.w*v0.w
             + v1.x*v1.x + v1.y*v1.y + v1.z*v1.z + v1.w*v1.w;
    int4 pk;
    pk.x = (int)pkbf(v0.x, v0.y); pk.y = (int)pkbf(v0.z, v0.w);
    pk.z = (int)pkbf(v1.x, v1.y); pk.w = (int)pkbf(v1.z, v1.w);
    *(int4*)(sBn + r*256 + ((hh ^ (r & 7)) << 4)) = pk;
    ss += __shfl_xor(ss, 1, 64);
    ss += __shfl_xor(ss, 2, 64);
    ss += __shfl_xor(ss, 4, 64);
    ss += __shfl_xor(ss, 8, 64);
    if (hh == 0) k2n[r] = ss;
}

// ============ Path A: bf16 MFMA distance GEMM -> u8 log-bins ============
// v8 (unchanged): full-b blocks. sA holds ALL 512 h-rows (128 KB). Per
// 32-key tile each wave does 32 MFMAs. Deferred bins stores. Keys read once.
__global__ __launch_bounds__(512, 1) void gemm4_kernel(
    const float* __restrict__ keys, const unsigned short* __restrict__ hbf,
    const float* __restrict__ q2, unsigned char* __restrict__ bins)
{
    const int blk = blockIdx.x, a = blockIdx.y;
    const int tid = threadIdx.x;
    const int lane = tid & 63, w = tid >> 6;
    const int lm = lane & 15, kh = lane >> 4;

    __shared__ __align__(16) short sA[512*128];   // h 512x128 bf16, swizzled (128 KB)
    __shared__ __align__(16) short sB[2][32*128]; // keys 32x128 bf16 dbuf (16 KB)
    __shared__ float q2s[512];
    __shared__ float k2s[2][32];

    // stage sA: 8192 int4 chunks, 16 per thread, coalesced; XOR-swizzled
    #pragma unroll
    for (int u = 0; u < 16; u++) {
        int idx = u*512 + tid;
        int rr = idx >> 4, cc = idx & 15;
        int4 gv = ((const int4*)hbf)[rr*16 + cc];
        *(int4*)((char*)sA + rr*256 + ((cc ^ (rr & 7)) << 4)) = gv;
    }
    q2s[tid] = q2[tid];

    const int r = tid >> 4, hh = tid & 15;   // 32 rows x 16 chunks
    const float* ka = keys + (size_t)a*C_*DIM;
    const int nbase = blk*(GT4*GTPB4);

    float4 lv[2];
    load2(lv, ka, nbase + r, hh);
    conv_store32(lv, (char*)&sB[0][0], k2s[0], r, hh);
    __syncthreads();   // sA + q2s + tile0 staged

    // loop-invariant store pointers: row = b (bcol), col = n
    unsigned char* rp0; unsigned char* rp1; unsigned char* rp2; unsigned char* rp3;
    {
        unsigned char* base = bins + (size_t)(a*B_)*C_ + kh*4;
        rp0 = base + (size_t)(w*64 +  0 + lm)*C_;
        rp1 = base + (size_t)(w*64 + 16 + lm)*C_;
        rp2 = base + (size_t)(w*64 + 32 + lm)*C_;
        rp3 = base + (size_t)(w*64 + 48 + lm)*C_;
    }

    unsigned pkp[8];   // deferred bins (j=0..3 x i=0..1), fully unrolled idx
    #pragma unroll
    for (int u = 0; u < 8; u++) pkp[u] = 0;
    int n0_prev = 0;

    int cur = 0;
    for (int t = 0; t < GTPB4; t++) {
        const int n0 = nbase + t*GT4;
        const bool more = (t + 1 < GTPB4);

        // issue next tile's fp32 loads first (oldest in queue; fly under MFMA)
        if (more) load2(lv, ka, n0 + GT4 + r, hh);
        // deferred store of previous tile's bins (retire during this tile)
        if (t > 0) {
            *(unsigned*)(rp0 + n0_prev     ) = pkp[0];
            *(unsigned*)(rp0 + n0_prev + 16) = pkp[1];
            *(unsigned*)(rp1 + n0_prev     ) = pkp[2];
            *(unsigned*)(rp1 + n0_prev + 16) = pkp[3];
            *(unsigned*)(rp2 + n0_prev     ) = pkp[4];
            *(unsigned*)(rp2 + n0_prev + 16) = pkp[5];
            *(unsigned*)(rp3 + n0_prev     ) = pkp[6];
            *(unsigned*)(rp3 + n0_prev + 16) = pkp[7];
        }

        f32x4 acc[2][4];
        #pragma unroll
        for (int i = 0; i < 2; i++)
            #pragma unroll
            for (int j = 0; j < 4; j++) acc[i][j] = (f32x4){0.f, 0.f, 0.f, 0.f};

        const char* sBc = (const char*)&sB[cur][0];
        #pragma unroll
        for (int kst = 0; kst < 4; kst++) {
            bf16x8 af[2], bfv[4];
            #pragma unroll
            for (int i = 0; i < 2; i++) {     // A = keys (n rows 0..31)
                int nr = i*16 + lm;
                af[i] = *(const bf16x8*)(sBc + nr*256 + ((((kst<<2) + kh) ^ (nr & 7)) << 4));
            }
            #pragma unroll
            for (int j = 0; j < 4; j++) {     // B = h (wave's 64 b cols)
                int br = w*64 + j*16 + lm;
                bfv[j] = *(const bf16x8*)((const char*)sA + br*256 + ((((kst<<2) + kh) ^ (br & 7)) << 4));
            }
            #pragma unroll
            for (int i = 0; i < 2; i++)
                #pragma unroll
                for (int j = 0; j < 4; j++)
                    acc[i][j] = __builtin_amdgcn_mfma_f32_16x16x32_bf16(af[i], bfv[j], acc[i][j], 0, 0, 0);
        }

        // compute this tile's packed bins (held in regs across the barrier)
        {
            float4 kq0 = *(const float4*)&k2s[cur][kh*4];        // i=0 quad
            float4 kq1 = *(const float4*)&k2s[cur][16 + kh*4];   // i=1 quad
            #pragma unroll
            for (int j = 0; j < 4; j++) {
                float q2v = q2s[w*64 + j*16 + lm];
                #pragma unroll
                for (int i = 0; i < 2; i++) {
                    float4 kq = (i == 0) ? kq0 : kq1;
                    unsigned pk = 0;
                    #pragma unroll
                    for (int rg = 0; rg < 4; rg++) {
                        float kv = (rg == 0) ? kq.x : (rg == 1) ? kq.y : (rg == 2) ? kq.z : kq.w;
                        float d2v = (q2v + kv) - 2.0f*acc[i][j][rg];
                        float dc = fminf(fmaxf(d2v, 16.0f), 4095.0f);
                        unsigned bin = (__float_as_uint(dc) >> 19) - 2096u;  // [0,127]
                        pk |= bin << (8*rg);
                    }
                    pkp[j*2 + i] = pk;
                }
            }
            n0_prev = n0;
        }

        // convert prefetched regs -> other buffer (vmcnt wait lands here,
        // after the MFMA+epilogue phase covered the load latency)
        if (more) conv_store32(lv, (char*)&sB[cur ^ 1][0], k2s[cur ^ 1], r, hh);
        __syncthreads();   // ds_writes visible; reads of sB[cur] retired
        cur ^= 1;
    }
    // final tile's stores
    *(unsigned*)(rp0 + n0_prev     ) = pkp[0];
    *(unsigned*)(rp0 + n0_prev + 16) = pkp[1];
    *(unsigned*)(rp1 + n0_prev     ) = pkp[2];
    *(unsigned*)(rp1 + n0_prev + 16) = pkp[3];
    *(unsigned*)(rp2 + n0_prev     ) = pkp[4];
    *(unsigned*)(rp2 + n0_prev + 16) = pkp[5];
    *(unsigned*)(rp3 + n0_prev     ) = pkp[6];
    *(unsigned*)(rp3 + n0_prev + 16) = pkp[7];
}

// ============ Path A: fused hist + tau + collect + exact top-K ============
// v9: (1) scan1 software-pipelined: two 4-chunk register batches, next
// batch's loads issued before processing current -> 4-8 loads in flight
// (was 1). (2) scan1 also records per-chunk min bin (minb, 12.5KB LDS);
// scan2 loads a chunk from global ONLY if minb[ch] <= tb (~7% of chunks).
// Candidate set provably identical; counts/margin/extraction unchanged.
__global__ __launch_bounds__(512) void finish_kernel(
    const unsigned char* __restrict__ bins, const float* __restrict__ keys,
    const double* __restrict__ h64, const float* __restrict__ mem_values,
    float* __restrict__ out_values, double* __restrict__ val64)
{
    const int q = blockIdx.x;          // a*B_ + b (bins row)
    const int a = q >> 9, b = q & 511;
    const int p = b*A_ + a;            // output index
    const int tid = threadIdx.x;

    __shared__ unsigned hist_s[NBIN_A*32];
    __shared__ unsigned hc[NBIN_A];
    __shared__ double hd[DIM];
    __shared__ unsigned char minb[ROWCH + 12];
    __shared__ int    cidx[CAP_A];
    __shared__ double d2s[CAP_A];
    __shared__ float  vs[CAP_A];
    __shared__ double redv[8];
    __shared__ int    redi8[8];
    __shared__ double acc_w, acc_wv;
    __shared__ unsigned cnt_s;
    __shared__ int thr_s;

    for (int i = tid; i < NBIN_A*32; i += 512) hist_s[i] = 0;
    for (int i = tid; i < DIM; i += 512) hd[i] = h64[(size_t)b*DIM + i];
    if (tid == 0) { cnt_s = 0; acc_w = 0.0; acc_wv = 0.0; }
    __syncthreads();

    const uint4* row = (const uint4*)(bins + (size_t)q*C_);
    const int rep = tid & 31;          // bank = rep -> conflict-free spread

    // histogram + per-chunk min for one 16B chunk
    auto proc1 = [&](uint4 v, int ch) {
        unsigned d[4] = {v.x, v.y, v.z, v.w};
        unsigned mn = 255u;
        #pragma unroll
        for (int e = 0; e < 4; e++) {
            unsigned x = d[e];
            unsigned b0 =  x        & 127u;
            unsigned b1 = (x >>  8) & 127u;
            unsigned b2 = (x >> 16) & 127u;
            unsigned b3 = (x >> 24) & 127u;
            atomicAdd(&hist_s[b0*32 + rep], 1u);
            atomicAdd(&hist_s[b1*32 + rep], 1u);
            atomicAdd(&hist_s[b2*32 + rep], 1u);
            atomicAdd(&hist_s[b3*32 + rep], 1u);
            unsigned m01 = b0 < b1 ? b0 : b1;
            unsigned m23 = b2 < b3 ? b2 : b3;
            unsigned m = m01 < m23 ? m01 : m23;
            mn = m < mn ? m : mn;
        }
        minb[ch] = (unsigned char)mn;
    };

    // scan 1: 24 full strides of 512 (6 groups of 4, software-pipelined)
    // + 212 tail
    {
        uint4 va[4], vb[4];
        #pragma unroll
        for (int u = 0; u < 4; u++) va[u] = row[u*512 + tid];
        #pragma unroll
        for (int g = 0; g < 6; g += 2) {
            #pragma unroll
            for (int u = 0; u < 4; u++) vb[u] = row[((g+1)*4 + u)*512 + tid];
            #pragma unroll
            for (int u = 0; u < 4; u++) proc1(va[u], (g*4 + u)*512 + tid);
            if (g + 2 < 6) {
                #pragma unroll
                for (int u = 0; u < 4; u++) va[u] = row[((g+2)*4 + u)*512 + tid];
            }
            #pragma unroll
            for (int u = 0; u < 4; u++) proc1(vb[u], ((g+1)*4 + u)*512 + tid);
        }
        if (tid < ROWCH - 24*512) {    // 212 tail chunks
            int ch = 24*512 + tid;
            proc1(row[ch], ch);
        }
    }
    __syncthreads();
    if (tid < NBIN_A) {
        unsigned s = 0;
        #pragma unroll
        for (int r2 = 0; r2 < 32; r2++) s += hist_s[tid*32 + r2];
        hc[tid] = s;
    }
    __syncthreads();
    if (tid == 0) {
        unsigned cum = 0; int jsel = NBIN_A-1;
        for (int j = 0; j < NBIN_A; j++) { cum += hc[j]; if (cum >= K_) { jsel = j; break; } }
        unsigned c1 = cum + (jsel+1 < NBIN_A ? hc[jsel+1] : 0u);
        unsigned c2 = c1  + (jsel+2 < NBIN_A ? hc[jsel+2] : 0u);
        int jt = (c2 <= 768u) ? jsel+2 : jsel+1;   // capture margin
        if (jt > NBIN_A-1) jt = NBIN_A-1;
        thr_s = jt + 1;
    }
    __syncthreads();
    const unsigned thr  = (unsigned)thr_s;         // select bytes < thr
    const unsigned addv = (128u - thr) * 0x01010101u;
    // scan 2: minb-gated collect (loads only chunks containing a candidate)
    for (int ch = tid; ch < ROWCH; ch += 512) {
        if ((unsigned)minb[ch] < thr) {
            uint4 v = row[ch];
            unsigned d[4] = {v.x, v.y, v.z, v.w};
            #pragma unroll
            for (int e = 0; e < 4; e++) {
                unsigned m = (d[e] + addv) & 0x80808080u;
                if (m != 0x80808080u) {
                    #pragma unroll
                    for (int by = 0; by < 4; by++) {
                        if (!((m >> (8*by + 7)) & 1u)) {
                            unsigned pos = atomicAdd(&cnt_s, 1u);
                            if (pos < CAP_A) cidx[pos] = ch*16 + e*4 + by;
                        }
                    }
                }
            }
        }
    }
    __syncthreads();
    int n = (int)cnt_s; if (n > CAP_A) n = CAP_A;

    // exact fp64 distances
    for (int i = tid; i < n; i += 512) {
        int c = cidx[i];
        const float4* kr = (const float4*)(keys + ((size_t)a*C_ + c)*DIM);
        double s0 = 0.0, s1 = 0.0;
        #pragma unroll 4
        for (int kq = 0; kq < 32; kq++) {
            float4 kv = kr[kq];
            double d0 = hd[4*kq+0] - (double)kv.x;
            double d1 = hd[4*kq+1] - (double)kv.y;
            double d2 = hd[4*kq+2] - (double)kv.z;
            double d3 = hd[4*kq+3] - (double)kv.w;
            s0 += d0*d0 + d1*d1; s1 += d2*d2 + d3*d3;
        }
        d2s[i] = s0 + s1;
        vs[i]  = mem_values[(size_t)a*C_ + c];
    }
    __syncthreads();

    // serial top-K extraction (shuffle butterfly, 2 barriers/iter)
    int kk = n < K_ ? n : K_;
    for (int t = 0; t < kk; t++) {
        double best = 1e300; int bi = -1;
        for (int i = tid; i < n; i += 512)
            if (d2s[i] < best) { best = d2s[i]; bi = i; }
        #pragma unroll
        for (int off = 32; off > 0; off >>= 1) {
            double ov = __shfl_xor(best, off, 64);
            int    oi = __shfl_xor(bi,   off, 64);
            if (ov < best) { best = ov; bi = oi; }
        }
        int wv = tid >> 6;
        if ((tid & 63) == 0) { redv[wv] = best; redi8[wv] = bi; }
        __syncthreads();
        if (tid == 0) {
            double bv = redv[0]; int wi = redi8[0];
            #pragma unroll
            for (int u = 1; u < 8; u++)
                if (redv[u] < bv) { bv = redv[u]; wi = redi8[u]; }
            double d = d2s[wi]; if (d < 0.0) d = 0.0;
            double wgt = 1.0 / (d + DELTA);
            acc_w += wgt; acc_wv += wgt * (double)vs[wi];
            d2s[wi] = 2e300;
        }
        __syncthreads();
    }
    if (tid == 0) {
        double v = acc_wv / acc_w;
        out_values[p] = (float)v;
        val64[p] = v;
    }
}

// ============ Path B (round-1 fallback) kernels ============
__global__ __launch_bounds__(256) void k2_kernel(const float* __restrict__ keys,
                                                 float* __restrict__ k2)
{
    int r = blockIdx.x*4 + (threadIdx.x >> 6);
    int lane = threadIdx.x & 63;
    float2 v = ((const float2*)keys)[(size_t)r*64 + lane];
    float s = v.x*v.x + v.y*v.y;
    #pragma unroll
    for (int off = 32; off > 0; off >>= 1) s += __shfl_down(s, off, 64);
    if (lane == 0) k2[r] = s;
}

template<int MODE>
__global__ __launch_bounds__(256) void pass_kernel(
    const float* __restrict__ keys, const float* __restrict__ h32,
    const float* __restrict__ q2,   const float* __restrict__ k2,
    unsigned* __restrict__ hist,    const float* __restrict__ tau,
    unsigned* __restrict__ cnt,     int* __restrict__ cand)
{
    const int bt = blockIdx.x;
    const int ch = blockIdx.y;
    const int a  = blockIdx.z;
    const int b0 = bt*BM_B;
    const int tid = threadIdx.x;
    const int tx = tid & 31, ty = tid >> 5;

    __shared__ float4 hs4[BM_B*33];
    __shared__ float4 ks4[BN_B*33];
    __shared__ float  q2s[BM_B];
    __shared__ float  taus[BM_B];
    __shared__ unsigned hist_s[MODE == 0 ? BM_B*NBIN_B : 1];

    #pragma unroll
    for (int q = 0; q < BM_B*32/256; q++) {
        int flat = q*256 + tid; int row = flat >> 5, kq = flat & 31;
        hs4[row*33 + kq] = ((const float4*)h32)[(size_t)(b0+row)*32 + kq];
    }
    if (tid < BM_B) {
        q2s[tid] = q2[b0+tid];
        if (MODE == 1) taus[tid] = tau[(b0+tid)*A_ + a];
    }
    if (MODE == 0) for (int i = tid; i < BM_B*NBIN_B; i += 256) hist_s[i] = 0;
    const float* __restrict__ k2g = k2 + (size_t)a*C_;

    for (int t = 0; t < TPC_B; t++) {
        int n0 = ch*CHUNK_B + t*BN_B;
        if (n0 >= C_) break;
        __syncthreads();
        #pragma unroll
        for (int q = 0; q < 16; q++) {
            int flat = q*256 + tid; int row = flat >> 5, kq = flat & 31;
            int nr = n0 + row; if (nr >= C_) nr = C_-1;
            ks4[row*33 + kq] = ((const float4*)keys)[((size_t)a*C_ + nr)*32 + kq];
        }
        __syncthreads();

        float acc[8][4];
        #pragma unroll
        for (int i = 0; i < 8; i++)
            #pragma unroll
            for (int j = 0; j < 4; j++) acc[i][j] = 0.0f;

        for (int kq = 0; kq < 32; kq++) {
            float4 hv[8], kv[4];
            #pragma unroll
            for (int i = 0; i < 8; i++) hv[i] = hs4[(ty*8+i)*33 + kq];
            #pragma unroll
            for (int j = 0; j < 4; j++) kv[j] = ks4[(j*32+tx)*33 + kq];
            #pragma unroll
            for (int i = 0; i < 8; i++)
                #pragma unroll
                for (int j = 0; j < 4; j++)
                    acc[i][j] += hv[i].x*kv[j].x + hv[i].y*kv[j].y
                               + hv[i].z*kv[j].z + hv[i].w*kv[j].w;
        }

        #pragma unroll
        for (int i = 0; i < 8; i++) {
            int bl = ty*8 + i;
            float q2b = q2s[bl];
            #pragma unroll
            for (int j = 0; j < 4; j++) {
                int n = n0 + j*32 + tx;
                if (n < C_) {
                    float d2f = fmaxf(q2b + k2g[n] - 2.0f*acc[i][j], 0.0f);
                    if (MODE == 0) {
                        int bin = (int)(__float_as_uint(d2f + 1.0f) >> 19) - 2032;
                        bin = bin < 0 ? 0 : (bin > NBIN_B-1 ? NBIN_B-1 : bin);
                        atomicAdd(&hist_s[bl*NBIN_B + bin], 1u);
                    } else {
                        if (d2f < taus[bl]) {
                            int p = (b0+bl)*A_ + a;
                            unsigned pos = atomicAdd(&cnt[p], 1u);
                            if (pos < CAP_B) cand[(size_t)p*CAP_B + pos] = n;
                        }
                    }
                }
            }
        }
    }
    if (MODE == 0) {
        __syncthreads();
        for (int i = tid; i < BM_B*NBIN_B; i += 256) {
            unsigned v = hist_s[i];
            if (v) {
                int bl = i / NBIN_B, bin = i % NBIN_B;
                atomicAdd(&hist[(size_t)((b0+bl)*A_ + a)*NBIN_B + bin], v);
            }
        }
    }
}

__global__ __launch_bounds__(256) void tauB_kernel(const unsigned* __restrict__ hist,
                                                   float* __restrict__ tau)
{
    int p = blockIdx.x*256 + threadIdx.x;
    if (p >= B_*A_) return;
    const unsigned* hp = hist + (size_t)p*NBIN_B;
    unsigned cum = 0; int jsel = NBIN_B-1;
    for (int j = 0; j < NBIN_B; j++) { cum += hp[j]; if (cum >= K_) { jsel = j; break; } }
    tau[p] = __uint_as_float((unsigned)(2034 + jsel) << 19) - 1.0f;
}

// ============ Path B: exact fp64 top-K + NEC weighted value ============
__global__ __launch_bounds__(256) void select_kernel(
    const float* __restrict__ keys, const double* __restrict__ h64,
    const float* __restrict__ mem_values,
    const unsigned* __restrict__ cnt, const int* __restrict__ cand,
    float* __restrict__ out_values, double* __restrict__ val64, int cap)
{
    int p = blockIdx.x; int b = p / A_, a = p % A_;
    int tid = threadIdx.x;
    __shared__ double hd[DIM];
    __shared__ double d2s[CAP_A];
    __shared__ float  vs[CAP_A];
    __shared__ double redv[4];
    __shared__ int    redi4[4];
    __shared__ double acc_w, acc_wv;

    for (int i = tid; i < DIM; i += 256) hd[i] = h64[(size_t)b*DIM + i];
    if (tid == 0) { acc_w = 0.0; acc_wv = 0.0; }
    __syncthreads();

    int n = (int)cnt[p]; if (n > cap) n = cap;
    for (int i = tid; i < n; i += 256) {
        int c = cand[(size_t)p*cap + i];
        const float4* kr = (const float4*)(keys + ((size_t)a*C_ + c)*DIM);
        double s0 = 0.0, s1 = 0.0;
        #pragma unroll 4
        for (int kq = 0; kq < 32; kq++) {
            float4 kv = kr[kq];
            double d0 = hd[4*kq+0] - (double)kv.x;
            double d1 = hd[4*kq+1] - (double)kv.y;
            double d2 = hd[4*kq+2] - (double)kv.z;
            double d3 = hd[4*kq+3] - (double)kv.w;
            s0 += d0*d0 + d1*d1; s1 += d2*d2 + d3*d3;
        }
        d2s[i] = s0 + s1;
        vs[i]  = mem_values[(size_t)a*C_ + c];
    }
    __syncthreads();

    int kk = n < K_ ? n : K_;
    for (int t = 0; t < kk; t++) {
        double best = 1e300; int bi = -1;
        for (int i = tid; i < n; i += 256)
            if (d2s[i] < best) { best = d2s[i]; bi = i; }
        #pragma unroll
        for (int off = 32; off > 0; off >>= 1) {
            double ov = __shfl_xor(best, off, 64);
            int    oi = __shfl_xor(bi,   off, 64);
            if (ov < best) { best = ov; bi = oi; }
        }
        int wv = tid >> 6;
        if ((tid & 63) == 0) { redv[wv] = best; redi4[wv] = bi; }
        __syncthreads();
        if (tid == 0) {
            double bv = redv[0]; int wi = redi4[0];
            if (redv[1] < bv) { bv = redv[1]; wi = redi4[1]; }
            if (redv[2] < bv) { bv = redv[2]; wi = redi4[2]; }
            if (redv[3] < bv) { bv = redv[3]; wi = redi4[3]; }
            double d = d2s[wi]; if (d < 0.0) d = 0.0;
            double wgt = 1.0 / (d + DELTA);
            acc_w += wgt; acc_wv += wgt * (double)vs[wi];
            d2s[wi] = 2e300;
        }
        __syncthreads();
    }
    if (tid == 0) {
        double v = acc_wv / acc_w;
        out_values[p] = (float)v;
        val64[p] = v;
    }
}

__global__ void argmax_kernel(const double* __restrict__ val64, float* __restrict__ out)
{
    int b = blockIdx.x*blockDim.x + threadIdx.x;
    if (b >= B_) return;
    double v0 = val64[b*A_+0], v1 = val64[b*A_+1], v2 = val64[b*A_+2];
    int bi = 0; double bv = v0;
    if (v1 > bv) { bv = v1; bi = 1; }
    if (v2 > bv) { bv = v2; bi = 2; }
    out[B_*A_ + b] = (float)bi;
}

// ============ host ============
extern "C" void kernel_launch(void* const* d_in, const int* in_sizes, int n_in,
                              void* d_out, int out_size, void* d_ws, size_t ws_size,
                              hipStream_t stream)
{
    const float* x    = (const float*)d_in[0];
    const float* W1   = (const float*)d_in[1];
    const float* b1   = (const float*)d_in[2];
    const float* W2   = (const float*)d_in[3];
    const float* b2   = (const float*)d_in[4];
    const float* W3   = (const float*)d_in[5];
    const float* b3   = (const float*)d_in[6];
    const float* W4   = (const float*)d_in[7];
    const float* b4   = (const float*)d_in[8];
    const float* keys = (const float*)d_in[9];
    const float* memv = (const float*)d_in[10];

    char* ws = (char*)d_ws;

    if (ws_size >= NEED_A) {
        // -------- Path A: MFMA gemm -> bins -> fused finish --------
        double*         h64  = (double*)        (ws + AOFF_H64);
        float*          h32  = (float*)         (ws + AOFF_H32);
        unsigned short* hbf  = (unsigned short*)(ws + AOFF_HBF);
        float*          q2   = (float*)         (ws + AOFF_Q2);
        double*         v64  = (double*)        (ws + AOFF_V64);
        unsigned char*  bins = (unsigned char*) (ws + AOFF_BINS);

        mlp_kernel<<<B_, 128, 0, stream>>>(x, W1, b1, W2, b2, W3, b3, W4, b4, h32, hbf, h64, q2);
        gemm4_kernel<<<dim3(NBLK4, A_), 512, 0, stream>>>(keys, hbf, q2, bins);
        finish_kernel<<<B_*A_, 512, 0, stream>>>(bins, keys, h64, memv, (float*)d_out, v64);
        argmax_kernel<<<2, 256, 0, stream>>>(v64, (float*)d_out);
    } else {
        // -------- Path B: round-1 proven fp32 two-pass --------
        float*          h32  = (float*)         (ws + BOFF_H32);
        double*         h64  = (double*)        (ws + BOFF_H64);
        float*          q2   = (float*)         (ws + BOFF_Q2);
        float*          k2   = (float*)         (ws + BOFF_K2);
        unsigned*       hist = (unsigned*)      (ws + BOFF_HIST);
        float*          tau  = (float*)         (ws + BOFF_TAU);
        unsigned*       cnt  = (unsigned*)      (ws + BOFF_CNT);
        double*         v64  = (double*)        (ws + BOFF_V64);
        int*            cand = (int*)           (ws + BOFF_CAND);
        unsigned short* hbf  = (unsigned short*)(ws + BOFF_CAND); // scratch

        hipMemsetAsync(ws + BOFF_HIST, 0, (BOFF_CNT + B_*A_*4) - BOFF_HIST, stream);

        mlp_kernel<<<B_, 128, 0, stream>>>(x, W1, b1, W2, b2, W3, b3, W4, b4, h32, hbf, h64, q2);
        k2_kernel<<<(A_*C_)/4, 256, 0, stream>>>(keys, k2);
        pass_kernel<0><<<dim3(B_/BM_B, NCH_B, A_), 256, 0, stream>>>(keys, h32, q2, k2, hist, nullptr, nullptr, nullptr);
        tauB_kernel<<<(B_*A_ + 255)/256, 256, 0, stream>>>(hist, tau);
        pass_kernel<1><<<dim3(B_/BM_B, NCH_B, A_), 256, 0, stream>>>(keys, h32, q2, k2, nullptr, tau, cnt, cand);
        select_kernel<<<B_*A_, 256, 0, stream>>>(keys, h64, memv, cnt, cand, (float*)d_out, v64, CAP_B);
        argmax_kernel<<<2, 256, 0, stream>>>(v64, (float*)d_out);
    }
}